// Round 11
// baseline (287.720 us; speedup 1.0000x reference)
//
#include <hip/hip_runtime.h>

#define DI __device__ __forceinline__

using bf16x8 = __attribute__((ext_vector_type(8))) __bf16;
using bf16x4 = __attribute__((ext_vector_type(4))) __bf16;
using f32x4  = __attribute__((ext_vector_type(4))) float;

typedef unsigned short u16;
typedef unsigned int   u32;

static constexpr float SM_SCALE = 0.0625f;
static constexpr float LAMBD    = 1.0f / 512.0f;

// ---------------- ws layout ----------------
static constexpr size_t OFF_THETA  = 0;
static constexpr size_t OFF_PROTOT = 262144;
static constexpr size_t OFF_PROTO  = 524288;
static constexpr size_t OFF_FC1    = 786432;
static constexpr size_t OFF_FC2    = 1310720;
static constexpr size_t OFF_O      = 1835008;
static constexpr size_t OFF_PSUM   = 2097152;   // f32 [512][512]
static constexpr size_t OFF_PSQ    = 3145728;
static constexpr size_t OFF_AFF    = 4194304;
static constexpr size_t OFF_A2     = 8388608;   // bf16 [32768][512] = 32MiB (big-ws path)
static constexpr size_t WS_NEED    = OFF_A2 + 33554432;

// d_out scratch (split path): A1 [0,32MiB); Q [32,48); R [32,64) (Q dead first)
static constexpr size_t OUT_X = 0;
static constexpr size_t OUT_Y = 33554432;

// ---------------- LDS ----------------
static constexpr int AB0 = 0;
static constexpr int AB1 = 32768;
static constexpr int SCR = 65536;
static constexpr int SMEM_B = 70144;

DI u16 f2b(float f) {
  union { float f; u32 u; } c; c.f = f;
  u32 r = c.u + 0x7FFFu + ((c.u >> 16) & 1u);
  return (u16)(r >> 16);
}

__global__ __launch_bounds__(256) void prep_kernel(
    const float* __restrict__ theta, const float* __restrict__ proto,
    const float* __restrict__ fc1,   const float* __restrict__ fc2,
    const float* __restrict__ ow,    char* __restrict__ ws)
{
  u16* w_theta  = (u16*)(ws + OFF_THETA);
  u16* w_protoT = (u16*)(ws + OFF_PROTOT);
  u16* w_proto  = (u16*)(ws + OFF_PROTO);
  u16* w_fc1    = (u16*)(ws + OFF_FC1);
  u16* w_fc2    = (u16*)(ws + OFF_FC2);
  u16* w_o      = (u16*)(ws + OFF_O);
  for (int i = blockIdx.x * blockDim.x + threadIdx.x; i < 1048576;
       i += gridDim.x * blockDim.x) {
    if (i < 131072) { w_theta[i] = f2b(theta[i]); }
    else if (i < 262144) { int j = i - 131072; int k = j >> 8, f = j & 255;
                           w_protoT[j] = f2b(proto[f * 512 + k]); }
    else if (i < 393216) { int j = i - 262144; w_proto[j] = f2b(proto[j]); }
    else if (i < 655360) { int j = i - 393216; w_fc1[j] = f2b(fc1[j]); }
    else if (i < 917504) { int j = i - 655360; w_fc2[j] = f2b(fc2[j]); }
    else                 { int j = i - 917504; w_o[j]   = f2b(ow[j]); }
  }
}

DI void bar() {
  asm volatile("s_waitcnt lgkmcnt(0)" ::: "memory");
  __builtin_amdgcn_s_barrier();
}

DI bf16x8 ld_frag(const char* base, int row, int kbyte) {
  return *(const bf16x8*)(base + row * 512 + (kbyte ^ ((row & 7) << 4)));
}

#define MFMA __builtin_amdgcn_mfma_f32_16x16x32_bf16

DI float red16(float v) {
  #pragma unroll
  for (int s = 1; s < 16; s <<= 1) v += __shfl_xor(v, s, 64);
  return v;
}

DI void row_round(char* smem, int round, float (&part)[4][4], float (&res)[4][4],
                  int w, int l, int tid) {
  float* rrb = (float*)(smem + SCR + round * 2048);
  float* rfb = (float*)(smem + SCR + 4096 + round * 256);
  const int g = l >> 4;
  if ((l & 15) == 0) {
    #pragma unroll
    for (int r0 = 0; r0 < 4; ++r0)
      #pragma unroll
      for (int rr = 0; rr < 4; ++rr)
        rrb[(r0 * 16 + g * 4 + rr) * 8 + w] = part[r0][rr];
  }
  bar();
  if (tid < 64) {
    float m = 0.0f;
    #pragma unroll
    for (int q = 0; q < 8; ++q) m += rrb[tid * 8 + q];
    rfb[tid] = m;
  }
  bar();
  #pragma unroll
  for (int r0 = 0; r0 < 4; ++r0)
    #pragma unroll
    for (int rr = 0; rr < 4; ++rr)
      res[r0][rr] = rfb[r0 * 16 + g * 4 + rr];
}

// =================================================================================
// ============================ SPLIT-PATH HELPERS =================================
// =================================================================================
DI void in_stage(char* win, const __bf16* __restrict__ g, int m0, int S, int coff, int tid) {
  #pragma unroll
  for (int k = 0; k < 4; ++k) {
    const int idx = k * 512 + tid;
    const int row = idx >> 5, ch = idx & 31;
    bf16x8 v = *(const bf16x8*)(g + (size_t)(m0 + row) * S + coff + ch * 8);
    *(bf16x8*)(win + row * 512 + ((ch * 16) ^ ((row & 7) << 4))) = v;
  }
}
DI void out_stage(const char* win, __bf16* __restrict__ g, int m0, int S, int coff, int tid) {
  #pragma unroll
  for (int k = 0; k < 4; ++k) {
    const int idx = k * 512 + tid;
    const int row = idx >> 5, ch = idx & 31;
    bf16x8 v = *(const bf16x8*)(win + row * 512 + ((ch * 16) ^ ((row & 7) << 4)));
    *(bf16x8*)(g + (size_t)(m0 + row) * S + coff + ch * 8) = v;
  }
}

template<int CT>
DI void gemm512(f32x4 (&acc)[4][CT], const char* a0, const char* a1,
                const __bf16* __restrict__ wbase, int w, int l) {
  const int g = l >> 4, lr = l & 15;
  constexpr int D = 4;
  const __bf16* wp[CT];
  #pragma unroll
  for (int j = 0; j < CT; ++j)
    wp[j] = wbase + (size_t)(((w + 8 * j) << 4) + lr) * 512 + g * 8;
  bf16x8 bb[D][CT];
  #pragma unroll
  for (int i = 0; i < D; ++i)
    #pragma unroll
    for (int j = 0; j < CT; ++j)
      bb[i][j] = *(const bf16x8*)(wp[j] + i * 32);
  #pragma unroll
  for (int s = 0; s < 16; ++s) {
    const char* aw = (s < 8) ? a0 : a1;
    bf16x8 af[4];
    #pragma unroll
    for (int r = 0; r < 4; ++r)
      af[r] = ld_frag(aw, r * 16 + lr, (s & 7) * 64 + g * 16);
    #pragma unroll
    for (int j = 0; j < CT; ++j)
      #pragma unroll
      for (int r = 0; r < 4; ++r)
        acc[r][j] = MFMA(af[r], bb[s % D][j], acc[r][j], 0, 0, 0);
    if (s + D < 16) {
      #pragma unroll
      for (int j = 0; j < CT; ++j)
        bb[s % D][j] = *(const bf16x8*)(wp[j] + (s + D) * 32);
    }
  }
}

template<int CT>
DI void gemm256s(f32x4 (&acc)[4][CT], const char* awin,
                 const __bf16* __restrict__ wbase, int w, int l) {
  const int g = l >> 4, lr = l & 15;
  constexpr int D = 4;
  const __bf16* wp[CT];
  #pragma unroll
  for (int j = 0; j < CT; ++j)
    wp[j] = wbase + (size_t)(((w + 8 * j) << 4) + lr) * 256 + g * 8;
  bf16x8 bb[D][CT];
  #pragma unroll
  for (int i = 0; i < D; ++i)
    #pragma unroll
    for (int j = 0; j < CT; ++j)
      bb[i][j] = *(const bf16x8*)(wp[j] + i * 32);
  #pragma unroll
  for (int s = 0; s < 8; ++s) {
    bf16x8 af[4];
    #pragma unroll
    for (int r = 0; r < 4; ++r)
      af[r] = ld_frag(awin, r * 16 + lr, s * 64 + g * 16);
    #pragma unroll
    for (int j = 0; j < CT; ++j)
      #pragma unroll
      for (int r = 0; r < 4; ++r)
        acc[r][j] = MFMA(af[r], bb[s % D][j], acc[r][j], 0, 0, 0);
    if (s + D < 8) {
      #pragma unroll
      for (int j = 0; j < CT; ++j)
        bb[s % D][j] = *(const bf16x8*)(wp[j] + (s + D) * 32);
    }
  }
}

DI void gemmGh(f32x4 (&acc)[2][4], const char* rwin,
               const __bf16* __restrict__ ow, int gh, int w, int l) {
  const int g = l >> 4, lr = l & 15;
  const __bf16* ap[2];
  #pragma unroll
  for (int i = 0; i < 2; ++i)
    ap[i] = ow + (size_t)(((w + 8 * (2 * gh + i)) << 4) + lr) * 256 + g * 8;
  bf16x8 ar[2][2];
  #pragma unroll
  for (int d = 0; d < 2; ++d)
    #pragma unroll
    for (int i = 0; i < 2; ++i)
      ar[d][i] = *(const bf16x8*)(ap[i] + d * 32);
  #pragma unroll
  for (int s = 0; s < 8; ++s) {
    bf16x8 bv[4];
    #pragma unroll
    for (int ct = 0; ct < 4; ++ct)
      bv[ct] = ld_frag(rwin, ct * 16 + lr, s * 64 + g * 16);
    #pragma unroll
    for (int i = 0; i < 2; ++i)
      #pragma unroll
      for (int ct = 0; ct < 4; ++ct)
        acc[i][ct] = MFMA(ar[s & 1][i], bv[ct], acc[i][ct], 0, 0, 0);
    if (s + 2 < 8) {
      #pragma unroll
      for (int i = 0; i < 2; ++i)
        ar[s & 1][i] = *(const bf16x8*)(ap[i] + (s + 2) * 32);
    }
  }
}

template<int CT>
DI void store_accw(char* aw, const f32x4 (&v)[4][CT], int w, int l) {
  #pragma unroll
  for (int j = 0; j < CT; ++j) {
    const int col = (w + 8 * j) * 16 + (l & 15);
    #pragma unroll
    for (int r0 = 0; r0 < 4; ++r0)
      #pragma unroll
      for (int rr = 0; rr < 4; ++rr) {
        const int row = r0 * 16 + (l >> 4) * 4 + rr;
        *(__bf16*)(aw + row * 512 + ((col * 2) ^ ((row & 7) << 4))) = (__bf16)v[r0][j][rr];
      }
  }
}
DI void store_bh(char* aw, const bf16x4 (&v)[4][2], int w, int l) {
  #pragma unroll
  for (int j = 0; j < 2; ++j) {
    const int col = (w + 8 * j) * 16 + (l & 15);
    #pragma unroll
    for (int r0 = 0; r0 < 4; ++r0)
      #pragma unroll
      for (int rr = 0; rr < 4; ++rr) {
        const int row = r0 * 16 + (l >> 4) * 4 + rr;
        *(__bf16*)(aw + row * 512 + ((col * 2) ^ ((row & 7) << 4))) = v[r0][j][rr];
      }
  }
}

// ================= K1: Q = X @ theta^T =================
__global__ __launch_bounds__(512, 4) void k1_q(
    const float* __restrict__ x, const char* __restrict__ ws, char* __restrict__ ob)
{
  extern __shared__ __align__(16) char smem[];
  const int tid = threadIdx.x, w = tid >> 6, l = tid & 63;
  const int bid = blockIdx.x, m0 = bid << 6, n = m0 >> 12, p0 = m0 & 4095;
  char* ab0 = smem + AB0; char* ab1 = smem + AB1;
  const __bf16* w_theta = (const __bf16*)(ws + OFF_THETA);
  __bf16* Q = (__bf16*)(ob + OUT_Y);

  #pragma unroll
  for (int q = 0; q < 8; ++q) {
    const int c  = q * 64 + (tid >> 3);
    const int cl = c & 255;
    char* aw = (c < 256) ? ab0 : ab1;
    const int j0 = (tid & 7) * 8;
    const float* xp = x + ((size_t)(n * 512 + c)) * 4096 + (size_t)(p0 + j0);
    f32x4 v0 = *(const f32x4*)xp;
    f32x4 v1 = *(const f32x4*)(xp + 4);
    #pragma unroll
    for (int i = 0; i < 8; ++i) {
      const float f = (i < 4) ? v0[i] : v1[i - 4];
      const int row = j0 + i;
      *(__bf16*)(aw + row * 512 + ((cl * 2) ^ ((row & 7) << 4))) = (__bf16)f;
    }
  }
  bar();
  f32x4 acc[4][2];
  #pragma unroll
  for (int a = 0; a < 4; ++a) { acc[a][0] = f32x4{0,0,0,0}; acc[a][1] = f32x4{0,0,0,0}; }
  gemm512<2>(acc, ab0, ab1, w_theta, w, l);
  bar();
  store_accw<2>(ab0, acc, w, l);
  bar();
  out_stage(ab0, Q, m0, 256, 0, tid);
}

// ================= K2: softmax/shrink/renorm -> A1 =================
__global__ __launch_bounds__(512, 4) void k2_attn(
    const char* __restrict__ ws, char* __restrict__ ob)
{
  extern __shared__ __align__(16) char smem[];
  const int tid = threadIdx.x, w = tid >> 6, l = tid & 63;
  const int g = l >> 4, lr = l & 15;
  const int m0 = blockIdx.x << 6;
  char* ab0 = smem + AB0; char* ab1 = smem + AB1;
  const __bf16* w_protoT = (const __bf16*)(ws + OFF_PROTOT);
  const __bf16* Q  = (const __bf16*)(ob + OUT_Y);
  __bf16* A1 = (__bf16*)(ob + OUT_X);

  in_stage(ab0, Q, m0, 256, 0, tid);
  bar();

  float se[4][4];
  #pragma unroll
  for (int r0 = 0; r0 < 4; ++r0)
    #pragma unroll
    for (int rr = 0; rr < 4; ++rr) se[r0][rr] = 0.f;

  #pragma unroll
  for (int h = 0; h < 2; ++h) {
    f32x4 accB[4][2];
    #pragma unroll
    for (int a = 0; a < 4; ++a) { accB[a][0] = f32x4{0,0,0,0}; accB[a][1] = f32x4{0,0,0,0}; }
    gemm256s<2>(accB, ab0, w_protoT + (size_t)h * 256 * 256, w, l);
    if (h == 1) bar();
    char* wn = h ? ab0 : ab1;
    #pragma unroll
    for (int j = 0; j < 2; ++j) {
      const int col = (w + 8 * j) * 16 + lr;
      #pragma unroll
      for (int r0 = 0; r0 < 4; ++r0)
        #pragma unroll
        for (int rr = 0; rr < 4; ++rr) {
          const float e = __expf(accB[r0][j][rr] * SM_SCALE);
          se[r0][rr] += e;
          const int row = r0 * 16 + g * 4 + rr;
          *(__bf16*)(wn + row * 512 + ((col * 2) ^ ((row & 7) << 4))) = (__bf16)e;
        }
    }
  }
  #pragma unroll
  for (int r0 = 0; r0 < 4; ++r0)
    #pragma unroll
    for (int rr = 0; rr < 4; ++rr) se[r0][rr] = red16(se[r0][rr]);

  float rres[4][4];
  row_round(smem, 0, se, rres, w, l, tid);

  #pragma unroll
  for (int r0 = 0; r0 < 4; ++r0)
    #pragma unroll
    for (int rr = 0; rr < 4; ++rr) {
      const float rinv = 1.0f / rres[r0][rr];
      const int row = r0 * 16 + g * 4 + rr;
      float s2 = 0.f;
      #pragma unroll
      for (int ft = 0; ft < 4; ++ft) {
        char* wn = (ft < 2) ? ab1 : ab0;
        const int col = (w + 8 * (ft & 1)) * 16 + lr;
        __bf16* p = (__bf16*)(wn + row * 512 + ((col * 2) ^ ((row & 7) << 4)));
        const float s = (float)(*p) * rinv;
        const float t = s - LAMBD;
        const float a = __fdividef(fmaxf(t, 0.f) * s, fabsf(t) + 1e-12f);
        *p = (__bf16)a;
        s2 += a;
      }
      se[r0][rr] = red16(s2);
    }
  row_round(smem, 1, se, rres, w, l, tid);

  #pragma unroll
  for (int r0 = 0; r0 < 4; ++r0)
    #pragma unroll
    for (int rr = 0; rr < 4; ++rr) {
      const float rinv = 1.0f / (rres[r0][rr] + 1e-12f);
      const int row = r0 * 16 + g * 4 + rr;
      #pragma unroll
      for (int ft = 0; ft < 4; ++ft) {
        char* wn = (ft < 2) ? ab1 : ab0;
        const int col = (w + 8 * (ft & 1)) * 16 + lr;
        __bf16* p = (__bf16*)(wn + row * 512 + ((col * 2) ^ ((row & 7) << 4)));
        *p = (__bf16)((float)(*p) * rinv);
      }
    }
  bar();
  out_stage(ab1, A1, m0, 512, 0,   tid);
  out_stage(ab0, A1, m0, 512, 256, tid);
}

// ================= K3: R = relu(A1 @ fc1^T + b1) =================
__global__ __launch_bounds__(512, 4) void k3_fc1(
    const char* __restrict__ ws, const float* __restrict__ fc1b, char* __restrict__ ob)
{
  extern __shared__ __align__(16) char smem[];
  const int tid = threadIdx.x, w = tid >> 6, l = tid & 63;
  const int lr = l & 15;
  const int m0 = blockIdx.x << 6;
  char* ab0 = smem + AB0; char* ab1 = smem + AB1;
  const __bf16* w_fc1 = (const __bf16*)(ws + OFF_FC1);
  const __bf16* A1 = (const __bf16*)(ob + OUT_X);
  __bf16* R = (__bf16*)(ob + OUT_Y);

  in_stage(ab0, A1, m0, 512, 0,   tid);
  in_stage(ab1, A1, m0, 512, 256, tid);
  bar();

  bf16x4 prb[4][2];
  f32x4 accd[4][2];
  #pragma unroll
  for (int rh = 0; rh < 2; ++rh) {
    #pragma unroll
    for (int a = 0; a < 4; ++a) { accd[a][0] = f32x4{0,0,0,0}; accd[a][1] = f32x4{0,0,0,0}; }
    gemm512<2>(accd, ab0, ab1, w_fc1 + (size_t)rh * 256 * 512, w, l);
    if (rh == 0) {
      #pragma unroll
      for (int j = 0; j < 2; ++j) {
        const float b1 = fc1b[(w + 8 * j) * 16 + lr];
        #pragma unroll
        for (int r0 = 0; r0 < 4; ++r0)
          #pragma unroll
          for (int rr = 0; rr < 4; ++rr)
            prb[r0][j][rr] = (__bf16)fmaxf(accd[r0][j][rr] + b1, 0.f);
      }
    }
  }
  bar();
  store_bh(ab0, prb, w, l);
  {
    bf16x4 t[4][2];
    #pragma unroll
    for (int j = 0; j < 2; ++j) {
      const float b1 = fc1b[256 + (w + 8 * j) * 16 + lr];
      #pragma unroll
      for (int r0 = 0; r0 < 4; ++r0)
        #pragma unroll
        for (int rr = 0; rr < 4; ++rr)
          t[r0][j][rr] = (__bf16)fmaxf(accd[r0][j][rr] + b1, 0.f);
    }
    store_bh(ab1, t, w, l);
  }
  bar();
  out_stage(ab0, R, m0, 512, 0,   tid);
  out_stage(ab1, R, m0, 512, 256, tid);
}

// ================= K4: A2 = A1 + R @ fc2^T + b2 -> WS (race-free) =================
__global__ __launch_bounds__(512, 4) void k4_fc2(
    const char* __restrict__ ws, const float* __restrict__ fc2b,
    char* __restrict__ ob, __bf16* __restrict__ A2)
{
  extern __shared__ __align__(16) char smem[];
  const int tid = threadIdx.x, w = tid >> 6, l = tid & 63;
  const int g = l >> 4, lr = l & 15;
  const int m0 = blockIdx.x << 6;
  char* ab0 = smem + AB0; char* ab1 = smem + AB1;
  const __bf16* w_fc2 = (const __bf16*)(ws + OFF_FC2);
  const __bf16* R  = (const __bf16*)(ob + OUT_Y);
  const __bf16* A1 = (const __bf16*)(ob + OUT_X);

  in_stage(ab0, R, m0, 512, 0,   tid);
  in_stage(ab1, R, m0, 512, 256, tid);
  bar();

  #pragma unroll
  for (int ch = 0; ch < 2; ++ch) {
    f32x4 acce[4][2];
    #pragma unroll
    for (int jj = 0; jj < 2; ++jj) {
      const float b2 = fc2b[ch * 256 + (w + 8 * jj) * 16 + lr];
      const int col = ch * 256 + (w + 8 * jj) * 16 + lr;
      #pragma unroll
      for (int r0 = 0; r0 < 4; ++r0)
        #pragma unroll
        for (int rr = 0; rr < 4; ++rr) {
          const int row = r0 * 16 + g * 4 + rr;
          acce[r0][jj][rr] = (float)A1[(size_t)(m0 + row) * 512 + col] + b2;
        }
    }
    gemm512<2>(acce, ab0, ab1, w_fc2 + (size_t)ch * 256 * 512, w, l);
    #pragma unroll
    for (int jj = 0; jj < 2; ++jj) {
      const int col = ch * 256 + (w + 8 * jj) * 16 + lr;
      #pragma unroll
      for (int r0 = 0; r0 < 4; ++r0)
        #pragma unroll
        for (int rr = 0; rr < 4; ++rr) {
          const int row = r0 * 16 + g * 4 + rr;
          A2[(size_t)(m0 + row) * 512 + col] = (__bf16)acce[r0][jj][rr];
        }
    }
  }
}

// ================= K56: Rd = A2@proto^T (LDS); y = gamma*o_w@Rd^T + x ============
__global__ __launch_bounds__(512, 4) void k56_out(
    const float* __restrict__ x, const char* __restrict__ ws,
    const float* __restrict__ gammap, const __bf16* __restrict__ A2,
    float* __restrict__ out, float* __restrict__ psum, float* __restrict__ psq)
{
  extern __shared__ __align__(16) char smem[];
  const int tid = threadIdx.x, w = tid >> 6, l = tid & 63;
  const int g = l >> 4, lr = l & 15;
  const int bid = blockIdx.x, m0 = bid << 6, n = m0 >> 12, p0 = m0 & 4095;
  char* ab0 = smem + AB0; char* ab1 = smem + AB1;
  const __bf16* w_proto = (const __bf16*)(ws + OFF_PROTO);
  const __bf16* w_o     = (const __bf16*)(ws + OFF_O);

  in_stage(ab0, A2, m0, 512, 0,   tid);
  in_stage(ab1, A2, m0, 512, 256, tid);
  bar();

  f32x4 accf[4][2];
  #pragma unroll
  for (int a = 0; a < 4; ++a) { accf[a][0] = f32x4{0,0,0,0}; accf[a][1] = f32x4{0,0,0,0}; }
  gemm512<2>(accf, ab0, ab1, w_proto, w, l);
  bar();
  store_accw<2>(ab0, accf, w, l);
  bar();

  const float gmm = gammap[0];
  #pragma unroll
  for (int gh = 0; gh < 2; ++gh) {
    f32x4 accg[2][4];
    #pragma unroll
    for (int a = 0; a < 2; ++a)
      #pragma unroll
      for (int b = 0; b < 4; ++b) accg[a][b] = f32x4{0,0,0,0};
    gemmGh(accg, ab0, w_o, gh, w, l);
    #pragma unroll
    for (int i = 0; i < 2; ++i) {
      #pragma unroll
      for (int rr = 0; rr < 4; ++rr) {
        const int c = (w + 8 * (2 * gh + i)) * 16 + g * 4 + rr;
        const size_t base = ((size_t)(n * 512 + c)) * 4096 + (size_t)p0;
        float sy = 0.f, sq = 0.f;
        #pragma unroll
        for (int ct = 0; ct < 4; ++ct) {
          const int ml = ct * 16 + lr;
          const float y = gmm * accg[i][ct][rr] + x[base + ml];
          out[base + ml] = y;
          sy += y; sq += y * y;
        }
        sy = red16(sy);
        sq = red16(sq);
        if (lr == 0) {
          psum[(size_t)c * 512 + bid] = sy;
          psq [(size_t)c * 512 + bid] = sq;
        }
      }
    }
  }
}

// =================================================================================
// ======================= FALLBACK: round-5 mega (proven 208us) ===================
// =================================================================================
template<int W, int CT>
DI void gemm_winF(f32x4 (&acc)[4][CT], const char* awin,
                  const __bf16* __restrict__ wbase, int col0, int kw0,
                  int w, int l) {
  const int g  = l >> 4;
  const int lr = l & 15;
  const __bf16* wp[CT];
  #pragma unroll
  for (int j = 0; j < CT; ++j)
    wp[j] = wbase + (size_t)(col0 + ((w + 8 * j) << 4) + lr) * W + kw0 + g * 8;
  bf16x8 bc[CT];
  #pragma unroll
  for (int j = 0; j < CT; ++j) bc[j] = *(const bf16x8*)wp[j];
  #pragma unroll
  for (int kk = 0; kk < 8; ++kk) {
    bf16x8 af[4];
    #pragma unroll
    for (int r0 = 0; r0 < 4; ++r0)
      af[r0] = ld_frag(awin, r0 * 16 + lr, kk * 64 + g * 16);
    bf16x8 bn[CT];
    if (kk < 7) {
      #pragma unroll
      for (int j = 0; j < CT; ++j) bn[j] = *(const bf16x8*)(wp[j] + (kk + 1) * 32);
    }
    #pragma unroll
    for (int j = 0; j < CT; ++j)
      #pragma unroll
      for (int r0 = 0; r0 < 4; ++r0)
        acc[r0][j] = MFMA(af[r0], bc[j], acc[r0][j], 0, 0, 0);
    if (kk < 7) {
      #pragma unroll
      for (int j = 0; j < CT; ++j) bc[j] = bn[j];
    }
  }
}

template<int CT>
DI void store_f32F(char* aw, const f32x4 (&v)[4][CT], int w, int l) {
  #pragma unroll
  for (int j = 0; j < CT; ++j) {
    const int col = (w + 8 * j) * 16 + (l & 15);
    #pragma unroll
    for (int r0 = 0; r0 < 4; ++r0)
      #pragma unroll
      for (int rr = 0; rr < 4; ++rr) {
        const int row = r0 * 16 + (l >> 4) * 4 + rr;
        *(__bf16*)(aw + row * 512 + ((col * 2) ^ ((row & 7) << 4))) = (__bf16)v[r0][j][rr];
      }
  }
}
DI void store_pairF(char* aw, const bf16x4 (&v)[4][4], int jb, int w, int l) {
  #pragma unroll
  for (int j = 0; j < 2; ++j) {
    const int col = (w + 8 * j) * 16 + (l & 15);
    #pragma unroll
    for (int r0 = 0; r0 < 4; ++r0)
      #pragma unroll
      for (int rr = 0; rr < 4; ++rr) {
        const int row = r0 * 16 + (l >> 4) * 4 + rr;
        *(__bf16*)(aw + row * 512 + ((col * 2) ^ ((row & 7) << 4))) = v[r0][jb + j][rr];
      }
  }
}
DI void store_pair2F(char* aw, const bf16x4 (&v)[4][2], int w, int l) {
  #pragma unroll
  for (int j = 0; j < 2; ++j) {
    const int col = (w + 8 * j) * 16 + (l & 15);
    #pragma unroll
    for (int r0 = 0; r0 < 4; ++r0)
      #pragma unroll
      for (int rr = 0; rr < 4; ++rr) {
        const int row = r0 * 16 + (l >> 4) * 4 + rr;
        *(__bf16*)(aw + row * 512 + ((col * 2) ^ ((row & 7) << 4))) = v[r0][j][rr];
      }
  }
}

__global__ __launch_bounds__(512, 4) void megaF_kernel(
    const float* __restrict__ x, const char* __restrict__ ws,
    const float* __restrict__ fc1b, const float* __restrict__ fc2b,
    const float* __restrict__ gammap, float* __restrict__ out,
    float* __restrict__ psum, float* __restrict__ psq)
{
  extern __shared__ __align__(16) char smem[];
  const int tid = threadIdx.x;
  const int w   = tid >> 6;
  const int l   = tid & 63;
  const int bid = blockIdx.x;
  const int m0  = bid << 6;
  const int n   = m0 >> 12;
  const int p0  = m0 & 4095;

  const __bf16* w_theta  = (const __bf16*)(ws + OFF_THETA);
  const __bf16* w_protoT = (const __bf16*)(ws + OFF_PROTOT);
  const __bf16* w_proto  = (const __bf16*)(ws + OFF_PROTO);
  const __bf16* w_fc1    = (const __bf16*)(ws + OFF_FC1);
  const __bf16* w_fc2    = (const __bf16*)(ws + OFF_FC2);
  const __bf16* w_o      = (const __bf16*)(ws + OFF_O);

  char* ab0 = smem + AB0;
  char* ab1 = smem + AB1;

  const f32x4 zz = {0.f, 0.f, 0.f, 0.f};

  f32x4 accq[4][2];
  #pragma unroll
  for (int a = 0; a < 4; ++a) { accq[a][0] = zz; accq[a][1] = zz; }
  #pragma unroll
  for (int ah = 0; ah < 2; ++ah) {
    bar();
    #pragma unroll
    for (int q = 0; q < 4; ++q) {
      const int cl = q * 64 + (tid >> 3);
      const int c  = ah * 256 + cl;
      const int j0 = (tid & 7) * 8;
      const float* xp = x + ((size_t)(n * 512 + c)) * 4096 + (size_t)(p0 + j0);
      f32x4 v0 = *(const f32x4*)xp;
      f32x4 v1 = *(const f32x4*)(xp + 4);
      #pragma unroll
      for (int i = 0; i < 8; ++i) {
        const float f = (i < 4) ? v0[i] : v1[i - 4];
        const int row = j0 + i;
        *(__bf16*)(ab0 + row * 512 + ((cl * 2) ^ ((row & 7) << 4))) = (__bf16)f;
      }
    }
    bar();
    gemm_winF<512, 2>(accq, ab0, w_theta, 0, ah * 256, w, l);
  }

  bar();
  store_f32F<2>(ab0, accq, w, l);
  bar();

  bf16x4 pe[4][4];
  float  se[4][4];
  #pragma unroll
  for (int r0 = 0; r0 < 4; ++r0)
    #pragma unroll
    for (int rr = 0; rr < 4; ++rr) se[r0][rr] = 0.f;
  #pragma unroll
  for (int h = 0; h < 2; ++h) {
    f32x4 accB[4][2];
    #pragma unroll
    for (int a = 0; a < 4; ++a) { accB[a][0] = zz; accB[a][1] = zz; }
    gemm_winF<256, 2>(accB, ab0, w_protoT, h * 256, 0, w, l);
    #pragma unroll
    for (int r0 = 0; r0 < 4; ++r0)
      #pragma unroll
      for (int j = 0; j < 2; ++j)
        #pragma unroll
        for (int rr = 0; rr < 4; ++rr) {
          const float e = __expf(accB[r0][j][rr] * SM_SCALE);
          pe[r0][2 * h + j][rr] = (__bf16)e;
          se[r0][rr] += e;
        }
  }
  {
    float rres[4][4];
    #pragma unroll
    for (int r0 = 0; r0 < 4; ++r0)
      #pragma unroll
      for (int rr = 0; rr < 4; ++rr) se[r0][rr] = red16(se[r0][rr]);
    row_round(smem, 0, se, rres, w, l, tid);
    #pragma unroll
    for (int r0 = 0; r0 < 4; ++r0)
      #pragma unroll
      for (int rr = 0; rr < 4; ++rr) {
        const float rinv = 1.0f / rres[r0][rr];
        float s2 = 0.f;
        #pragma unroll
        for (int ft = 0; ft < 4; ++ft) {
          const float s = (float)pe[r0][ft][rr] * rinv;
          const float t = s - LAMBD;
          const float a = __fdividef(fmaxf(t, 0.f) * s, fabsf(t) + 1e-12f);
          pe[r0][ft][rr] = (__bf16)a;
          s2 += a;
        }
        se[r0][rr] = red16(s2);
      }
    row_round(smem, 1, se, rres, w, l, tid);
    #pragma unroll
    for (int r0 = 0; r0 < 4; ++r0)
      #pragma unroll
      for (int rr = 0; rr < 4; ++rr) {
        const float rinv = 1.0f / (rres[r0][rr] + 1e-12f);
        #pragma unroll
        for (int ft = 0; ft < 4; ++ft)
          pe[r0][ft][rr] = (__bf16)((float)pe[r0][ft][rr] * rinv);
      }
  }

  bar();
  store_pairF(ab0, pe, 0, w, l);
  store_pairF(ab1, pe, 2, w, l);
  bar();

  bf16x4 prb[2][4][2];
  #pragma unroll
  for (int rh = 0; rh < 2; ++rh) {
    f32x4 accd[4][2];
    #pragma unroll
    for (int a = 0; a < 4; ++a) { accd[a][0] = zz; accd[a][1] = zz; }
    gemm_winF<512, 2>(accd, ab0, w_fc1, rh * 256, 0,   w, l);
    gemm_winF<512, 2>(accd, ab1, w_fc1, rh * 256, 256, w, l);
    #pragma unroll
    for (int j = 0; j < 2; ++j) {
      const float b1 = fc1b[rh * 256 + (w + 8 * j) * 16 + (l & 15)];
      #pragma unroll
      for (int r0 = 0; r0 < 4; ++r0)
        #pragma unroll
        for (int rr = 0; rr < 4; ++rr)
          prb[rh][r0][j][rr] = (__bf16)fmaxf(accd[r0][j][rr] + b1, 0.f);
    }
  }

  bar();
  store_pair2F(ab0, prb[0], w, l);
  store_pair2F(ab1, prb[1], w, l);
  bar();

  bf16x4 pab[4][4];
  #pragma unroll
  for (int ch = 0; ch < 2; ++ch) {
    f32x4 acce[4][2];
    #pragma unroll
    for (int jj = 0; jj < 2; ++jj) {
      const float b2 = fc2b[ch * 256 + (w + 8 * jj) * 16 + (l & 15)];
      #pragma unroll
      for (int r0 = 0; r0 < 4; ++r0)
        #pragma unroll
        for (int rr = 0; rr < 4; ++rr)
          acce[r0][jj][rr] = (float)pe[r0][2 * ch + jj][rr] + b2;
    }
    gemm_winF<512, 2>(acce, ab0, w_fc2, ch * 256, 0,   w, l);
    gemm_winF<512, 2>(acce, ab1, w_fc2, ch * 256, 256, w, l);
    #pragma unroll
    for (int r0 = 0; r0 < 4; ++r0)
      #pragma unroll
      for (int jj = 0; jj < 2; ++jj)
        #pragma unroll
        for (int rr = 0; rr < 4; ++rr) pab[r0][2 * ch + jj][rr] = (__bf16)acce[r0][jj][rr];
  }

  bar();
  store_pairF(ab0, pab, 0, w, l);
  store_pairF(ab1, pab, 2, w, l);
  bar();

  f32x4 accf[4][2];
  #pragma unroll
  for (int a = 0; a < 4; ++a) { accf[a][0] = zz; accf[a][1] = zz; }
  gemm_winF<512, 2>(accf, ab0, w_proto, 0, 0,   w, l);
  gemm_winF<512, 2>(accf, ab1, w_proto, 0, 256, w, l);

  bar();
  store_f32F<2>(ab0, accf, w, l);
  bar();

  f32x4 accg[4][4];
  #pragma unroll
  for (int a = 0; a < 4; ++a)
    #pragma unroll
    for (int b = 0; b < 4; ++b) accg[a][b] = zz;
  {
    const int g  = l >> 4;
    const int lr = l & 15;
    const __bf16* wp[4];
    #pragma unroll
    for (int j = 0; j < 4; ++j)
      wp[j] = w_o + (size_t)(((w + 8 * j) << 4) + lr) * 256 + g * 8;
    #pragma unroll
    for (int kk = 0; kk < 8; ++kk) {
      bf16x8 of[4];
      #pragma unroll
      for (int j = 0; j < 4; ++j) of[j] = *(const bf16x8*)(wp[j] + kk * 32);
      #pragma unroll
      for (int ct = 0; ct < 4; ++ct) {
        bf16x8 rdv = ld_frag(ab0, ct * 16 + lr, kk * 64 + g * 16);
        #pragma unroll
        for (int j = 0; j < 4; ++j)
          accg[j][ct] = MFMA(of[j], rdv, accg[j][ct], 0, 0, 0);
      }
    }
  }

  const float gmm = gammap[0];
  #pragma unroll
  for (int j = 0; j < 4; ++j) {
    #pragma unroll
    for (int rr = 0; rr < 4; ++rr) {
      const int c = (w + 8 * j) * 16 + (l >> 4) * 4 + rr;
      const size_t base = ((size_t)(n * 512 + c)) * 4096 + (size_t)p0;
      float sy = 0.f, sq = 0.f;
      #pragma unroll
      for (int ct = 0; ct < 4; ++ct) {
        const int ml = ct * 16 + (l & 15);
        const float y = gmm * accg[j][ct][rr] + x[base + ml];
        out[base + ml] = y;
        sy += y; sq += y * y;
      }
      sy = red16(sy);
      sq = red16(sq);
      if ((l & 15) == 0) {
        psum[(size_t)c * 512 + bid] = sy;
        psq [(size_t)c * 512 + bid] = sq;
      }
    }
  }
}

// ---------------- BN stats / apply ----------------
__global__ __launch_bounds__(256) void stats_kernel(
    const float* __restrict__ psum, const float* __restrict__ psq,
    const float* __restrict__ bnw,  const float* __restrict__ bnb,
    float* __restrict__ aff)
{
  const int c = blockIdx.x;
  const int t = threadIdx.x;
  float s = psum[(size_t)c * 512 + t] + psum[(size_t)c * 512 + t + 256];
  float q = psq [(size_t)c * 512 + t] + psq [(size_t)c * 512 + t + 256];
  #pragma unroll
  for (int sh = 1; sh < 64; sh <<= 1) {
    s += __shfl_xor(s, sh, 64);
    q += __shfl_xor(q, sh, 64);
  }
  __shared__ float ls[4], lq[4];
  const int wv = t >> 6;
  if ((t & 63) == 0) { ls[wv] = s; lq[wv] = q; }
  __syncthreads();
  if (t == 0) {
    const float S = ls[0] + ls[1] + ls[2] + ls[3];
    const float Q = lq[0] + lq[1] + lq[2] + lq[3];
    const float mean = S * (1.0f / 32768.0f);
    const float var  = Q * (1.0f / 32768.0f) - mean * mean;
    const float inv  = rsqrtf(var + 1e-5f);
    const float sc   = bnw[c] * inv;
    aff[2 * c]     = sc;
    aff[2 * c + 1] = bnb[c] - mean * sc;
  }
}

__global__ __launch_bounds__(256) void norm_kernel(float* __restrict__ out,
                                                   const float* __restrict__ aff)
{
  f32x4* p = (f32x4*)out;
  for (int i = blockIdx.x * blockDim.x + threadIdx.x; i < 4194304;
       i += gridDim.x * blockDim.x) {
    const int c = (i >> 10) & 511;
    const float sc = aff[2 * c], sh = aff[2 * c + 1];
    f32x4 v = p[i];
    #pragma unroll
    for (int k = 0; k < 4; ++k) v[k] = v[k] * sc + sh;
    p[i] = v;
  }
}

extern "C" void kernel_launch(void* const* d_in, const int* in_sizes, int n_in,
                              void* d_out, int out_size, void* d_ws, size_t ws_size,
                              hipStream_t stream) {
  const float* x     = (const float*)d_in[0];
  const float* theta = (const float*)d_in[1];
  const float* proto = (const float*)d_in[2];
  const float* fc1w  = (const float*)d_in[3];
  const float* fc1b  = (const float*)d_in[4];
  const float* fc2w  = (const float*)d_in[5];
  const float* fc2b  = (const float*)d_in[6];
  const float* ow    = (const float*)d_in[7];
  const float* gamma = (const float*)d_in[8];
  const float* bnw   = (const float*)d_in[9];
  const float* bnb   = (const float*)d_in[10];
  char*  ws   = (char*)d_ws;
  char*  ob   = (char*)d_out;
  float* out  = (float*)d_out;
  float* psum = (float*)(ws + OFF_PSUM);
  float* psq  = (float*)(ws + OFF_PSQ);
  float* aff  = (float*)(ws + OFF_AFF);

  prep_kernel<<<4096, 256, 0, stream>>>(theta, proto, fc1w, fc2w, ow, ws);

  const bool big_ws = (ws_size >= WS_NEED);

  if (big_ws) {
    __bf16* A2 = (__bf16*)(ws + OFF_A2);
    (void)hipFuncSetAttribute((const void*)k1_q,    hipFuncAttributeMaxDynamicSharedMemorySize, SMEM_B);
    (void)hipFuncSetAttribute((const void*)k2_attn, hipFuncAttributeMaxDynamicSharedMemorySize, SMEM_B);
    (void)hipFuncSetAttribute((const void*)k3_fc1,  hipFuncAttributeMaxDynamicSharedMemorySize, SMEM_B);
    (void)hipFuncSetAttribute((const void*)k4_fc2,  hipFuncAttributeMaxDynamicSharedMemorySize, SMEM_B);
    (void)hipFuncSetAttribute((const void*)k56_out, hipFuncAttributeMaxDynamicSharedMemorySize, SMEM_B);
    k1_q   <<<512, 512, SMEM_B, stream>>>(x, ws, ob);
    k2_attn<<<512, 512, SMEM_B, stream>>>(ws, ob);
    k3_fc1 <<<512, 512, SMEM_B, stream>>>(ws, fc1b, ob);
    k4_fc2 <<<512, 512, SMEM_B, stream>>>(ws, fc2b, ob, A2);
    k56_out<<<512, 512, SMEM_B, stream>>>(x, ws, gamma, A2, out, psum, psq);
  } else {
    (void)hipFuncSetAttribute((const void*)megaF_kernel,
                              hipFuncAttributeMaxDynamicSharedMemorySize, SMEM_B);
    megaF_kernel<<<512, 512, SMEM_B, stream>>>(x, ws, fc1b, fc2b, gamma, out, psum, psq);
  }

  stats_kernel<<<512, 256, 0, stream>>>(psum, psq, bnw, bnb, aff);
  norm_kernel<<<2048, 256, 0, stream>>>(out, aff);
}

// Round 12
// 282.857 us; speedup vs baseline: 1.0172x; 1.0172x over previous
//
#include <hip/hip_runtime.h>

#define DI __device__ __forceinline__

using bf16x8 = __attribute__((ext_vector_type(8))) __bf16;
using bf16x4 = __attribute__((ext_vector_type(4))) __bf16;
using f32x4  = __attribute__((ext_vector_type(4))) float;

typedef unsigned short u16;
typedef unsigned int   u32;

static constexpr float SM_SCALE = 0.0625f;
static constexpr float LAMBD    = 1.0f / 512.0f;

// ---------------- ws layout ----------------
static constexpr size_t OFF_THETA  = 0;
static constexpr size_t OFF_PROTOT = 262144;
static constexpr size_t OFF_PROTO  = 524288;
static constexpr size_t OFF_FC1    = 786432;
static constexpr size_t OFF_FC2    = 1310720;
static constexpr size_t OFF_O      = 1835008;
static constexpr size_t OFF_PSUM   = 2097152;   // f32 [512][512]
static constexpr size_t OFF_PSQ    = 3145728;
static constexpr size_t OFF_AFF    = 4194304;
static constexpr size_t OFF_A2     = 8388608;   // bf16 [32768][512] = 32MiB; Rd overlays cols 0..255
static constexpr size_t WS_NEED    = OFF_A2 + 33554432;

// d_out scratch (split path): A1 [0,32MiB); R [32,64MiB)
static constexpr size_t OUT_X = 0;
static constexpr size_t OUT_Y = 33554432;

// ---------------- LDS ----------------
static constexpr int AB0 = 0;
static constexpr int AB1 = 32768;
static constexpr int SCR = 65536;
static constexpr int SMEM_B  = 70144;   // k12 (+softmax scratch), megaF
static constexpr int SMEM_2W = 65536;   // k3/k4/k5
static constexpr int SMEM_1W = 32768;   // k6

DI u16 f2b(float f) {
  union { float f; u32 u; } c; c.f = f;
  u32 r = c.u + 0x7FFFu + ((c.u >> 16) & 1u);
  return (u16)(r >> 16);
}

__global__ __launch_bounds__(256) void prep_kernel(
    const float* __restrict__ theta, const float* __restrict__ proto,
    const float* __restrict__ fc1,   const float* __restrict__ fc2,
    const float* __restrict__ ow,    char* __restrict__ ws)
{
  u16* w_theta  = (u16*)(ws + OFF_THETA);
  u16* w_protoT = (u16*)(ws + OFF_PROTOT);
  u16* w_proto  = (u16*)(ws + OFF_PROTO);
  u16* w_fc1    = (u16*)(ws + OFF_FC1);
  u16* w_fc2    = (u16*)(ws + OFF_FC2);
  u16* w_o      = (u16*)(ws + OFF_O);
  for (int i = blockIdx.x * blockDim.x + threadIdx.x; i < 1048576;
       i += gridDim.x * blockDim.x) {
    if (i < 131072) { w_theta[i] = f2b(theta[i]); }
    else if (i < 262144) { int j = i - 131072; int k = j >> 8, f = j & 255;
                           w_protoT[j] = f2b(proto[f * 512 + k]); }
    else if (i < 393216) { int j = i - 262144; w_proto[j] = f2b(proto[j]); }
    else if (i < 655360) { int j = i - 393216; w_fc1[j] = f2b(fc1[j]); }
    else if (i < 917504) { int j = i - 655360; w_fc2[j] = f2b(fc2[j]); }
    else                 { int j = i - 917504; w_o[j]   = f2b(ow[j]); }
  }
}

DI void bar() {
  asm volatile("s_waitcnt lgkmcnt(0)" ::: "memory");
  __builtin_amdgcn_s_barrier();
}

DI bf16x8 ld_frag(const char* base, int row, int kbyte) {
  return *(const bf16x8*)(base + row * 512 + (kbyte ^ ((row & 7) << 4)));
}

#define MFMA __builtin_amdgcn_mfma_f32_16x16x32_bf16

DI float red16(float v) {
  #pragma unroll
  for (int s = 1; s < 16; s <<= 1) v += __shfl_xor(v, s, 64);
  return v;
}

DI void row_round(char* smem, int round, float (&part)[4][4], float (&res)[4][4],
                  int w, int l, int tid) {
  float* rrb = (float*)(smem + SCR + round * 2048);
  float* rfb = (float*)(smem + SCR + 4096 + round * 256);
  const int g = l >> 4;
  if ((l & 15) == 0) {
    #pragma unroll
    for (int r0 = 0; r0 < 4; ++r0)
      #pragma unroll
      for (int rr = 0; rr < 4; ++rr)
        rrb[(r0 * 16 + g * 4 + rr) * 8 + w] = part[r0][rr];
  }
  bar();
  if (tid < 64) {
    float m = 0.0f;
    #pragma unroll
    for (int q = 0; q < 8; ++q) m += rrb[tid * 8 + q];
    rfb[tid] = m;
  }
  bar();
  #pragma unroll
  for (int r0 = 0; r0 < 4; ++r0)
    #pragma unroll
    for (int rr = 0; rr < 4; ++rr)
      res[r0][rr] = rfb[r0 * 16 + g * 4 + rr];
}

// ---------------- staging helpers ----------------
DI void in_stage(char* win, const __bf16* __restrict__ g, int m0, int S, int coff, int tid) {
  #pragma unroll
  for (int k = 0; k < 4; ++k) {
    const int idx = k * 512 + tid;
    const int row = idx >> 5, ch = idx & 31;
    bf16x8 v = *(const bf16x8*)(g + (size_t)(m0 + row) * S + coff + ch * 8);
    *(bf16x8*)(win + row * 512 + ((ch * 16) ^ ((row & 7) << 4))) = v;
  }
}
DI void out_stage(const char* win, __bf16* __restrict__ g, int m0, int S, int coff, int tid) {
  #pragma unroll
  for (int k = 0; k < 4; ++k) {
    const int idx = k * 512 + tid;
    const int row = idx >> 5, ch = idx & 31;
    bf16x8 v = *(const bf16x8*)(win + row * 512 + ((ch * 16) ^ ((row & 7) << 4)));
    *(bf16x8*)(g + (size_t)(m0 + row) * S + coff + ch * 8) = v;
  }
}

template<int CT>
DI void gemm512(f32x4 (&acc)[4][CT], const char* a0, const char* a1,
                const __bf16* __restrict__ wbase, int w, int l) {
  const int g = l >> 4, lr = l & 15;
  constexpr int D = 4;
  const __bf16* wp[CT];
  #pragma unroll
  for (int j = 0; j < CT; ++j)
    wp[j] = wbase + (size_t)(((w + 8 * j) << 4) + lr) * 512 + g * 8;
  bf16x8 bb[D][CT];
  #pragma unroll
  for (int i = 0; i < D; ++i)
    #pragma unroll
    for (int j = 0; j < CT; ++j)
      bb[i][j] = *(const bf16x8*)(wp[j] + i * 32);
  #pragma unroll
  for (int s = 0; s < 16; ++s) {
    const char* aw = (s < 8) ? a0 : a1;
    bf16x8 af[4];
    #pragma unroll
    for (int r = 0; r < 4; ++r)
      af[r] = ld_frag(aw, r * 16 + lr, (s & 7) * 64 + g * 16);
    #pragma unroll
    for (int j = 0; j < CT; ++j)
      #pragma unroll
      for (int r = 0; r < 4; ++r)
        acc[r][j] = MFMA(af[r], bb[s % D][j], acc[r][j], 0, 0, 0);
    if (s + D < 16) {
      #pragma unroll
      for (int j = 0; j < CT; ++j)
        bb[s % D][j] = *(const bf16x8*)(wp[j] + (s + D) * 32);
    }
  }
}

template<int CT>
DI void gemm256s(f32x4 (&acc)[4][CT], const char* awin,
                 const __bf16* __restrict__ wbase, int w, int l) {
  const int g = l >> 4, lr = l & 15;
  constexpr int D = 4;
  const __bf16* wp[CT];
  #pragma unroll
  for (int j = 0; j < CT; ++j)
    wp[j] = wbase + (size_t)(((w + 8 * j) << 4) + lr) * 256 + g * 8;
  bf16x8 bb[D][CT];
  #pragma unroll
  for (int i = 0; i < D; ++i)
    #pragma unroll
    for (int j = 0; j < CT; ++j)
      bb[i][j] = *(const bf16x8*)(wp[j] + i * 32);
  #pragma unroll
  for (int s = 0; s < 8; ++s) {
    bf16x8 af[4];
    #pragma unroll
    for (int r = 0; r < 4; ++r)
      af[r] = ld_frag(awin, r * 16 + lr, s * 64 + g * 16);
    #pragma unroll
    for (int j = 0; j < CT; ++j)
      #pragma unroll
      for (int r = 0; r < 4; ++r)
        acc[r][j] = MFMA(af[r], bb[s % D][j], acc[r][j], 0, 0, 0);
    if (s + D < 8) {
      #pragma unroll
      for (int j = 0; j < CT; ++j)
        bb[s % D][j] = *(const bf16x8*)(wp[j] + (s + D) * 32);
    }
  }
}

DI void gemmGh(f32x4 (&acc)[2][4], const char* rwin,
               const __bf16* __restrict__ ow, int gh, int w, int l) {
  const int g = l >> 4, lr = l & 15;
  const __bf16* ap[2];
  #pragma unroll
  for (int i = 0; i < 2; ++i)
    ap[i] = ow + (size_t)(((w + 8 * (2 * gh + i)) << 4) + lr) * 256 + g * 8;
  bf16x8 ar[2][2];
  #pragma unroll
  for (int d = 0; d < 2; ++d)
    #pragma unroll
    for (int i = 0; i < 2; ++i)
      ar[d][i] = *(const bf16x8*)(ap[i] + d * 32);
  #pragma unroll
  for (int s = 0; s < 8; ++s) {
    bf16x8 bv[4];
    #pragma unroll
    for (int ct = 0; ct < 4; ++ct)
      bv[ct] = ld_frag(rwin, ct * 16 + lr, s * 64 + g * 16);
    #pragma unroll
    for (int i = 0; i < 2; ++i)
      #pragma unroll
      for (int ct = 0; ct < 4; ++ct)
        acc[i][ct] = MFMA(ar[s & 1][i], bv[ct], acc[i][ct], 0, 0, 0);
    if (s + 2 < 8) {
      #pragma unroll
      for (int i = 0; i < 2; ++i)
        ar[s & 1][i] = *(const bf16x8*)(ap[i] + (s + 2) * 32);
    }
  }
}

template<int CT>
DI void store_accw(char* aw, const f32x4 (&v)[4][CT], int w, int l) {
  #pragma unroll
  for (int j = 0; j < CT; ++j) {
    const int col = (w + 8 * j) * 16 + (l & 15);
    #pragma unroll
    for (int r0 = 0; r0 < 4; ++r0)
      #pragma unroll
      for (int rr = 0; rr < 4; ++rr) {
        const int row = r0 * 16 + (l >> 4) * 4 + rr;
        *(__bf16*)(aw + row * 512 + ((col * 2) ^ ((row & 7) << 4))) = (__bf16)v[r0][j][rr];
      }
  }
}
DI void store_bh(char* aw, const bf16x4 (&v)[4][2], int w, int l) {
  #pragma unroll
  for (int j = 0; j < 2; ++j) {
    const int col = (w + 8 * j) * 16 + (l & 15);
    #pragma unroll
    for (int r0 = 0; r0 < 4; ++r0)
      #pragma unroll
      for (int rr = 0; rr < 4; ++rr) {
        const int row = r0 * 16 + (l >> 4) * 4 + rr;
        *(__bf16*)(aw + row * 512 + ((col * 2) ^ ((row & 7) << 4))) = v[r0][j][rr];
      }
  }
}

// ================= K12: x -> Q (LDS-resident) -> softmax/shrink/renorm -> A1 ======
__global__ __launch_bounds__(512, 4) void k12_attn(
    const float* __restrict__ x, const char* __restrict__ ws, char* __restrict__ ob)
{
  extern __shared__ __align__(16) char smem[];
  const int tid = threadIdx.x, w = tid >> 6, l = tid & 63;
  const int g = l >> 4, lr = l & 15;
  const int bid = blockIdx.x, m0 = bid << 6, n = m0 >> 12, p0 = m0 & 4095;
  char* ab0 = smem + AB0; char* ab1 = smem + AB1;
  const __bf16* w_theta  = (const __bf16*)(ws + OFF_THETA);
  const __bf16* w_protoT = (const __bf16*)(ws + OFF_PROTOT);
  __bf16* A1 = (__bf16*)(ob + OUT_X);

  // stage x [64 px][512 ch] -> ab0+ab1
  #pragma unroll
  for (int q = 0; q < 8; ++q) {
    const int c  = q * 64 + (tid >> 3);
    const int cl = c & 255;
    char* aw = (c < 256) ? ab0 : ab1;
    const int j0 = (tid & 7) * 8;
    const float* xp = x + ((size_t)(n * 512 + c)) * 4096 + (size_t)(p0 + j0);
    f32x4 v0 = *(const f32x4*)xp;
    f32x4 v1 = *(const f32x4*)(xp + 4);
    #pragma unroll
    for (int i = 0; i < 8; ++i) {
      const float f = (i < 4) ? v0[i] : v1[i - 4];
      const int row = j0 + i;
      *(__bf16*)(aw + row * 512 + ((cl * 2) ^ ((row & 7) << 4))) = (__bf16)f;
    }
  }
  bar();

  // Q = X @ theta^T (stays in LDS)
  f32x4 accq[4][2];
  #pragma unroll
  for (int a = 0; a < 4; ++a) { accq[a][0] = f32x4{0,0,0,0}; accq[a][1] = f32x4{0,0,0,0}; }
  gemm512<2>(accq, ab0, ab1, w_theta, w, l);
  bar();                       // all x reads done
  store_accw<2>(ab0, accq, w, l);   // Q -> ab0
  bar();

  // logits halves -> e (bf16, to LDS), f32 row sums
  float se[4][4];
  #pragma unroll
  for (int r0 = 0; r0 < 4; ++r0)
    #pragma unroll
    for (int rr = 0; rr < 4; ++rr) se[r0][rr] = 0.f;

  #pragma unroll
  for (int h = 0; h < 2; ++h) {
    f32x4 accB[4][2];
    #pragma unroll
    for (int a = 0; a < 4; ++a) { accB[a][0] = f32x4{0,0,0,0}; accB[a][1] = f32x4{0,0,0,0}; }
    gemm256s<2>(accB, ab0, w_protoT + (size_t)h * 256 * 256, w, l);
    if (h == 1) bar();        // all Q reads done before overwriting ab0
    char* wn = h ? ab0 : ab1;
    #pragma unroll
    for (int j = 0; j < 2; ++j) {
      const int col = (w + 8 * j) * 16 + lr;
      #pragma unroll
      for (int r0 = 0; r0 < 4; ++r0)
        #pragma unroll
        for (int rr = 0; rr < 4; ++rr) {
          const float e = __expf(accB[r0][j][rr] * SM_SCALE);
          se[r0][rr] += e;
          const int row = r0 * 16 + g * 4 + rr;
          *(__bf16*)(wn + row * 512 + ((col * 2) ^ ((row & 7) << 4))) = (__bf16)e;
        }
    }
  }
  #pragma unroll
  for (int r0 = 0; r0 < 4; ++r0)
    #pragma unroll
    for (int rr = 0; rr < 4; ++rr) se[r0][rr] = red16(se[r0][rr]);

  float rres[4][4];
  row_round(smem, 0, se, rres, w, l, tid);

  // hard-shrink sweep (RMW own cells)
  #pragma unroll
  for (int r0 = 0; r0 < 4; ++r0)
    #pragma unroll
    for (int rr = 0; rr < 4; ++rr) {
      const float rinv = 1.0f / rres[r0][rr];
      const int row = r0 * 16 + g * 4 + rr;
      float s2 = 0.f;
      #pragma unroll
      for (int ft = 0; ft < 4; ++ft) {
        char* wn = (ft < 2) ? ab1 : ab0;
        const int col = (w + 8 * (ft & 1)) * 16 + lr;
        __bf16* p = (__bf16*)(wn + row * 512 + ((col * 2) ^ ((row & 7) << 4)));
        const float s = (float)(*p) * rinv;
        const float t = s - LAMBD;
        const float a = __fdividef(fmaxf(t, 0.f) * s, fabsf(t) + 1e-12f);
        *p = (__bf16)a;
        s2 += a;
      }
      se[r0][rr] = red16(s2);
    }
  row_round(smem, 1, se, rres, w, l, tid);

  // renorm sweep
  #pragma unroll
  for (int r0 = 0; r0 < 4; ++r0)
    #pragma unroll
    for (int rr = 0; rr < 4; ++rr) {
      const float rinv = 1.0f / (rres[r0][rr] + 1e-12f);
      const int row = r0 * 16 + g * 4 + rr;
      #pragma unroll
      for (int ft = 0; ft < 4; ++ft) {
        char* wn = (ft < 2) ? ab1 : ab0;
        const int col = (w + 8 * (ft & 1)) * 16 + lr;
        __bf16* p = (__bf16*)(wn + row * 512 + ((col * 2) ^ ((row & 7) << 4)));
        *p = (__bf16)((float)(*p) * rinv);
      }
    }
  bar();
  out_stage(ab1, A1, m0, 512, 0,   tid);   // cols 0..255 in ab1
  out_stage(ab0, A1, m0, 512, 256, tid);   // cols 256..511 in ab0
}

// ================= K3: R = relu(A1 @ fc1^T + b1) =================
__global__ __launch_bounds__(512, 4) void k3_fc1(
    const char* __restrict__ ws, const float* __restrict__ fc1b, char* __restrict__ ob)
{
  extern __shared__ __align__(16) char smem[];
  const int tid = threadIdx.x, w = tid >> 6, l = tid & 63;
  const int lr = l & 15;
  const int m0 = blockIdx.x << 6;
  char* ab0 = smem + AB0; char* ab1 = smem + AB1;
  const __bf16* w_fc1 = (const __bf16*)(ws + OFF_FC1);
  const __bf16* A1 = (const __bf16*)(ob + OUT_X);
  __bf16* R = (__bf16*)(ob + OUT_Y);

  in_stage(ab0, A1, m0, 512, 0,   tid);
  in_stage(ab1, A1, m0, 512, 256, tid);
  bar();

  bf16x4 prb[4][2];
  f32x4 accd[4][2];
  #pragma unroll
  for (int rh = 0; rh < 2; ++rh) {
    #pragma unroll
    for (int a = 0; a < 4; ++a) { accd[a][0] = f32x4{0,0,0,0}; accd[a][1] = f32x4{0,0,0,0}; }
    gemm512<2>(accd, ab0, ab1, w_fc1 + (size_t)rh * 256 * 512, w, l);
    if (rh == 0) {
      #pragma unroll
      for (int j = 0; j < 2; ++j) {
        const float b1 = fc1b[(w + 8 * j) * 16 + lr];
        #pragma unroll
        for (int r0 = 0; r0 < 4; ++r0)
          #pragma unroll
          for (int rr = 0; rr < 4; ++rr)
            prb[r0][j][rr] = (__bf16)fmaxf(accd[r0][j][rr] + b1, 0.f);
      }
    }
  }
  bar();
  store_bh(ab0, prb, w, l);
  {
    bf16x4 t[4][2];
    #pragma unroll
    for (int j = 0; j < 2; ++j) {
      const float b1 = fc1b[256 + (w + 8 * j) * 16 + lr];
      #pragma unroll
      for (int r0 = 0; r0 < 4; ++r0)
        #pragma unroll
        for (int rr = 0; rr < 4; ++rr)
          t[r0][j][rr] = (__bf16)fmaxf(accd[r0][j][rr] + b1, 0.f);
    }
    store_bh(ab1, t, w, l);
  }
  bar();
  out_stage(ab0, R, m0, 512, 0,   tid);
  out_stage(ab1, R, m0, 512, 256, tid);
}

// ================= K4: A2 = A1 + R @ fc2^T + b2 -> WS =================
__global__ __launch_bounds__(512, 4) void k4_fc2(
    const char* __restrict__ ws, const float* __restrict__ fc2b,
    char* __restrict__ ob, __bf16* __restrict__ A2)
{
  extern __shared__ __align__(16) char smem[];
  const int tid = threadIdx.x, w = tid >> 6, l = tid & 63;
  const int g = l >> 4, lr = l & 15;
  const int m0 = blockIdx.x << 6;
  char* ab0 = smem + AB0; char* ab1 = smem + AB1;
  const __bf16* w_fc2 = (const __bf16*)(ws + OFF_FC2);
  const __bf16* R  = (const __bf16*)(ob + OUT_Y);
  const __bf16* A1 = (const __bf16*)(ob + OUT_X);

  in_stage(ab0, R, m0, 512, 0,   tid);
  in_stage(ab1, R, m0, 512, 256, tid);
  bar();

  #pragma unroll
  for (int ch = 0; ch < 2; ++ch) {
    f32x4 acce[4][2];
    #pragma unroll
    for (int jj = 0; jj < 2; ++jj) {
      const float b2 = fc2b[ch * 256 + (w + 8 * jj) * 16 + lr];
      const int col = ch * 256 + (w + 8 * jj) * 16 + lr;
      #pragma unroll
      for (int r0 = 0; r0 < 4; ++r0)
        #pragma unroll
        for (int rr = 0; rr < 4; ++rr) {
          const int row = r0 * 16 + g * 4 + rr;
          acce[r0][jj][rr] = (float)A1[(size_t)(m0 + row) * 512 + col] + b2;
        }
    }
    gemm512<2>(acce, ab0, ab1, w_fc2 + (size_t)ch * 256 * 512, w, l);
    #pragma unroll
    for (int jj = 0; jj < 2; ++jj) {
      const int col = ch * 256 + (w + 8 * jj) * 16 + lr;
      #pragma unroll
      for (int r0 = 0; r0 < 4; ++r0)
        #pragma unroll
        for (int rr = 0; rr < 4; ++rr) {
          const int row = r0 * 16 + g * 4 + rr;
          A2[(size_t)(m0 + row) * 512 + col] = (__bf16)acce[r0][jj][rr];
        }
    }
  }
}

// ================= K5: Rd = A2 @ proto^T -> A2 buffer cols 0..255 (row-local) =====
__global__ __launch_bounds__(512, 4) void k5_rd(
    const char* __restrict__ ws, __bf16* __restrict__ A2)
{
  extern __shared__ __align__(16) char smem[];
  const int tid = threadIdx.x, w = tid >> 6, l = tid & 63;
  const int m0 = blockIdx.x << 6;
  char* ab0 = smem + AB0; char* ab1 = smem + AB1;
  const __bf16* w_proto = (const __bf16*)(ws + OFF_PROTO);

  in_stage(ab0, A2, m0, 512, 0,   tid);
  in_stage(ab1, A2, m0, 512, 256, tid);
  bar();                 // block's A2 rows fully in LDS -> global rows now dead

  f32x4 accf[4][2];
  #pragma unroll
  for (int a = 0; a < 4; ++a) { accf[a][0] = f32x4{0,0,0,0}; accf[a][1] = f32x4{0,0,0,0}; }
  gemm512<2>(accf, ab0, ab1, w_proto, w, l);
  bar();
  store_accw<2>(ab0, accf, w, l);
  bar();
  out_stage(ab0, A2, m0, 512, 0, tid);   // Rd overlays own rows, cols 0..255
}

// ================= K6: y = gamma * o_w @ Rd^T + x ; BN partials =================
__global__ __launch_bounds__(512, 4) void k6_out(
    const float* __restrict__ x, const char* __restrict__ ws,
    const float* __restrict__ gammap, const __bf16* __restrict__ A2,
    float* __restrict__ out, float* __restrict__ psum, float* __restrict__ psq)
{
  extern __shared__ __align__(16) char smem[];
  const int tid = threadIdx.x, w = tid >> 6, l = tid & 63;
  const int g = l >> 4, lr = l & 15;
  const int bid = blockIdx.x, m0 = bid << 6, n = m0 >> 12, p0 = m0 & 4095;
  char* ab0 = smem + AB0;
  const __bf16* w_o = (const __bf16*)(ws + OFF_O);

  in_stage(ab0, A2, m0, 512, 0, tid);    // Rd rows (cols 0..255 of A2 buffer)
  bar();

  const float gmm = gammap[0];
  #pragma unroll
  for (int gh = 0; gh < 2; ++gh) {
    f32x4 accg[2][4];
    #pragma unroll
    for (int a = 0; a < 2; ++a)
      #pragma unroll
      for (int b = 0; b < 4; ++b) accg[a][b] = f32x4{0,0,0,0};
    gemmGh(accg, ab0, w_o, gh, w, l);
    #pragma unroll
    for (int i = 0; i < 2; ++i) {
      #pragma unroll
      for (int rr = 0; rr < 4; ++rr) {
        const int c = (w + 8 * (2 * gh + i)) * 16 + g * 4 + rr;
        const size_t base = ((size_t)(n * 512 + c)) * 4096 + (size_t)p0;
        float sy = 0.f, sq = 0.f;
        #pragma unroll
        for (int ct = 0; ct < 4; ++ct) {
          const int ml = ct * 16 + lr;
          const float y = gmm * accg[i][ct][rr] + x[base + ml];
          out[base + ml] = y;
          sy += y; sq += y * y;
        }
        sy = red16(sy);
        sq = red16(sq);
        if (lr == 0) {
          psum[(size_t)c * 512 + bid] = sy;
          psq [(size_t)c * 512 + bid] = sq;
        }
      }
    }
  }
}

// =================================================================================
// ======================= FALLBACK: round-5 mega (proven 208us) ===================
// =================================================================================
template<int W, int CT>
DI void gemm_winF(f32x4 (&acc)[4][CT], const char* awin,
                  const __bf16* __restrict__ wbase, int col0, int kw0,
                  int w, int l) {
  const int g  = l >> 4;
  const int lr = l & 15;
  const __bf16* wp[CT];
  #pragma unroll
  for (int j = 0; j < CT; ++j)
    wp[j] = wbase + (size_t)(col0 + ((w + 8 * j) << 4) + lr) * W + kw0 + g * 8;
  bf16x8 bc[CT];
  #pragma unroll
  for (int j = 0; j < CT; ++j) bc[j] = *(const bf16x8*)wp[j];
  #pragma unroll
  for (int kk = 0; kk < 8; ++kk) {
    bf16x8 af[4];
    #pragma unroll
    for (int r0 = 0; r0 < 4; ++r0)
      af[r0] = ld_frag(awin, r0 * 16 + lr, kk * 64 + g * 16);
    bf16x8 bn[CT];
    if (kk < 7) {
      #pragma unroll
      for (int j = 0; j < CT; ++j) bn[j] = *(const bf16x8*)(wp[j] + (kk + 1) * 32);
    }
    #pragma unroll
    for (int j = 0; j < CT; ++j)
      #pragma unroll
      for (int r0 = 0; r0 < 4; ++r0)
        acc[r0][j] = MFMA(af[r0], bc[j], acc[r0][j], 0, 0, 0);
    if (kk < 7) {
      #pragma unroll
      for (int j = 0; j < CT; ++j) bc[j] = bn[j];
    }
  }
}

template<int CT>
DI void store_f32F(char* aw, const f32x4 (&v)[4][CT], int w, int l) {
  #pragma unroll
  for (int j = 0; j < CT; ++j) {
    const int col = (w + 8 * j) * 16 + (l & 15);
    #pragma unroll
    for (int r0 = 0; r0 < 4; ++r0)
      #pragma unroll
      for (int rr = 0; rr < 4; ++rr) {
        const int row = r0 * 16 + (l >> 4) * 4 + rr;
        *(__bf16*)(aw + row * 512 + ((col * 2) ^ ((row & 7) << 4))) = (__bf16)v[r0][j][rr];
      }
  }
}
DI void store_pairF(char* aw, const bf16x4 (&v)[4][4], int jb, int w, int l) {
  #pragma unroll
  for (int j = 0; j < 2; ++j) {
    const int col = (w + 8 * j) * 16 + (l & 15);
    #pragma unroll
    for (int r0 = 0; r0 < 4; ++r0)
      #pragma unroll
      for (int rr = 0; rr < 4; ++rr) {
        const int row = r0 * 16 + (l >> 4) * 4 + rr;
        *(__bf16*)(aw + row * 512 + ((col * 2) ^ ((row & 7) << 4))) = v[r0][jb + j][rr];
      }
  }
}
DI void store_pair2F(char* aw, const bf16x4 (&v)[4][2], int w, int l) {
  #pragma unroll
  for (int j = 0; j < 2; ++j) {
    const int col = (w + 8 * j) * 16 + (l & 15);
    #pragma unroll
    for (int r0 = 0; r0 < 4; ++r0)
      #pragma unroll
      for (int rr = 0; rr < 4; ++rr) {
        const int row = r0 * 16 + (l >> 4) * 4 + rr;
        *(__bf16*)(aw + row * 512 + ((col * 2) ^ ((row & 7) << 4))) = v[r0][j][rr];
      }
  }
}

__global__ __launch_bounds__(512, 4) void megaF_kernel(
    const float* __restrict__ x, const char* __restrict__ ws,
    const float* __restrict__ fc1b, const float* __restrict__ fc2b,
    const float* __restrict__ gammap, float* __restrict__ out,
    float* __restrict__ psum, float* __restrict__ psq)
{
  extern __shared__ __align__(16) char smem[];
  const int tid = threadIdx.x;
  const int w   = tid >> 6;
  const int l   = tid & 63;
  const int bid = blockIdx.x;
  const int m0  = bid << 6;
  const int n   = m0 >> 12;
  const int p0  = m0 & 4095;

  const __bf16* w_theta  = (const __bf16*)(ws + OFF_THETA);
  const __bf16* w_protoT = (const __bf16*)(ws + OFF_PROTOT);
  const __bf16* w_proto  = (const __bf16*)(ws + OFF_PROTO);
  const __bf16* w_fc1    = (const __bf16*)(ws + OFF_FC1);
  const __bf16* w_fc2    = (const __bf16*)(ws + OFF_FC2);
  const __bf16* w_o      = (const __bf16*)(ws + OFF_O);

  char* ab0 = smem + AB0;
  char* ab1 = smem + AB1;

  const f32x4 zz = {0.f, 0.f, 0.f, 0.f};

  f32x4 accq[4][2];
  #pragma unroll
  for (int a = 0; a < 4; ++a) { accq[a][0] = zz; accq[a][1] = zz; }
  #pragma unroll
  for (int ah = 0; ah < 2; ++ah) {
    bar();
    #pragma unroll
    for (int q = 0; q < 4; ++q) {
      const int cl = q * 64 + (tid >> 3);
      const int c  = ah * 256 + cl;
      const int j0 = (tid & 7) * 8;
      const float* xp = x + ((size_t)(n * 512 + c)) * 4096 + (size_t)(p0 + j0);
      f32x4 v0 = *(const f32x4*)xp;
      f32x4 v1 = *(const f32x4*)(xp + 4);
      #pragma unroll
      for (int i = 0; i < 8; ++i) {
        const float f = (i < 4) ? v0[i] : v1[i - 4];
        const int row = j0 + i;
        *(__bf16*)(ab0 + row * 512 + ((cl * 2) ^ ((row & 7) << 4))) = (__bf16)f;
      }
    }
    bar();
    gemm_winF<512, 2>(accq, ab0, w_theta, 0, ah * 256, w, l);
  }

  bar();
  store_f32F<2>(ab0, accq, w, l);
  bar();

  bf16x4 pe[4][4];
  float  se[4][4];
  #pragma unroll
  for (int r0 = 0; r0 < 4; ++r0)
    #pragma unroll
    for (int rr = 0; rr < 4; ++rr) se[r0][rr] = 0.f;
  #pragma unroll
  for (int h = 0; h < 2; ++h) {
    f32x4 accB[4][2];
    #pragma unroll
    for (int a = 0; a < 4; ++a) { accB[a][0] = zz; accB[a][1] = zz; }
    gemm_winF<256, 2>(accB, ab0, w_protoT, h * 256, 0, w, l);
    #pragma unroll
    for (int r0 = 0; r0 < 4; ++r0)
      #pragma unroll
      for (int j = 0; j < 2; ++j)
        #pragma unroll
        for (int rr = 0; rr < 4; ++rr) {
          const float e = __expf(accB[r0][j][rr] * SM_SCALE);
          pe[r0][2 * h + j][rr] = (__bf16)e;
          se[r0][rr] += e;
        }
  }
  {
    float rres[4][4];
    #pragma unroll
    for (int r0 = 0; r0 < 4; ++r0)
      #pragma unroll
      for (int rr = 0; rr < 4; ++rr) se[r0][rr] = red16(se[r0][rr]);
    row_round(smem, 0, se, rres, w, l, tid);
    #pragma unroll
    for (int r0 = 0; r0 < 4; ++r0)
      #pragma unroll
      for (int rr = 0; rr < 4; ++rr) {
        const float rinv = 1.0f / rres[r0][rr];
        float s2 = 0.f;
        #pragma unroll
        for (int ft = 0; ft < 4; ++ft) {
          const float s = (float)pe[r0][ft][rr] * rinv;
          const float t = s - LAMBD;
          const float a = __fdividef(fmaxf(t, 0.f) * s, fabsf(t) + 1e-12f);
          pe[r0][ft][rr] = (__bf16)a;
          s2 += a;
        }
        se[r0][rr] = red16(s2);
      }
    row_round(smem, 1, se, rres, w, l, tid);
    #pragma unroll
    for (int r0 = 0; r0 < 4; ++r0)
      #pragma unroll
      for (int rr = 0; rr < 4; ++rr) {
        const float rinv = 1.0f / (rres[r0][rr] + 1e-12f);
        #pragma unroll
        for (int ft = 0; ft < 4; ++ft)
          pe[r0][ft][rr] = (__bf16)((float)pe[r0][ft][rr] * rinv);
      }
  }

  bar();
  store_pairF(ab0, pe, 0, w, l);
  store_pairF(ab1, pe, 2, w, l);
  bar();

  bf16x4 prb[2][4][2];
  #pragma unroll
  for (int rh = 0; rh < 2; ++rh) {
    f32x4 accd[4][2];
    #pragma unroll
    for (int a = 0; a < 4; ++a) { accd[a][0] = zz; accd[a][1] = zz; }
    gemm_winF<512, 2>(accd, ab0, w_fc1, rh * 256, 0,   w, l);
    gemm_winF<512, 2>(accd, ab1, w_fc1, rh * 256, 256, w, l);
    #pragma unroll
    for (int j = 0; j < 2; ++j) {
      const float b1 = fc1b[rh * 256 + (w + 8 * j) * 16 + (l & 15)];
      #pragma unroll
      for (int r0 = 0; r0 < 4; ++r0)
        #pragma unroll
        for (int rr = 0; rr < 4; ++rr)
          prb[rh][r0][j][rr] = (__bf16)fmaxf(accd[r0][j][rr] + b1, 0.f);
    }
  }

  bar();
  store_pair2F(ab0, prb[0], w, l);
  store_pair2F(ab1, prb[1], w, l);
  bar();

  bf16x4 pab[4][4];
  #pragma unroll
  for (int ch = 0; ch < 2; ++ch) {
    f32x4 acce[4][2];
    #pragma unroll
    for (int jj = 0; jj < 2; ++jj) {
      const float b2 = fc2b[ch * 256 + (w + 8 * jj) * 16 + (l & 15)];
      #pragma unroll
      for (int r0 = 0; r0 < 4; ++r0)
        #pragma unroll
        for (int rr = 0; rr < 4; ++rr)
          acce[r0][jj][rr] = (float)pe[r0][2 * ch + jj][rr] + b2;
    }
    gemm_winF<512, 2>(acce, ab0, w_fc2, ch * 256, 0,   w, l);
    gemm_winF<512, 2>(acce, ab1, w_fc2, ch * 256, 256, w, l);
    #pragma unroll
    for (int r0 = 0; r0 < 4; ++r0)
      #pragma unroll
      for (int jj = 0; jj < 2; ++jj)
        #pragma unroll
        for (int rr = 0; rr < 4; ++rr) pab[r0][2 * ch + jj][rr] = (__bf16)acce[r0][jj][rr];
  }

  bar();
  store_pairF(ab0, pab, 0, w, l);
  store_pairF(ab1, pab, 2, w, l);
  bar();

  f32x4 accf[4][2];
  #pragma unroll
  for (int a = 0; a < 4; ++a) { accf[a][0] = zz; accf[a][1] = zz; }
  gemm_winF<512, 2>(accf, ab0, w_proto, 0, 0,   w, l);
  gemm_winF<512, 2>(accf, ab1, w_proto, 0, 256, w, l);

  bar();
  store_f32F<2>(ab0, accf, w, l);
  bar();

  f32x4 accg[4][4];
  #pragma unroll
  for (int a = 0; a < 4; ++a)
    #pragma unroll
    for (int b = 0; b < 4; ++b) accg[a][b] = zz;
  {
    const int g  = l >> 4;
    const int lr = l & 15;
    const __bf16* wp[4];
    #pragma unroll
    for (int j = 0; j < 4; ++j)
      wp[j] = w_o + (size_t)(((w + 8 * j) << 4) + lr) * 256 + g * 8;
    #pragma unroll
    for (int kk = 0; kk < 8; ++kk) {
      bf16x8 of[4];
      #pragma unroll
      for (int j = 0; j < 4; ++j) of[j] = *(const bf16x8*)(wp[j] + kk * 32);
      #pragma unroll
      for (int ct = 0; ct < 4; ++ct) {
        bf16x8 rdv = ld_frag(ab0, ct * 16 + lr, kk * 64 + g * 16);
        #pragma unroll
        for (int j = 0; j < 4; ++j)
          accg[j][ct] = MFMA(of[j], rdv, accg[j][ct], 0, 0, 0);
      }
    }
  }

  const float gmm = gammap[0];
  #pragma unroll
  for (int j = 0; j < 4; ++j) {
    #pragma unroll
    for (int rr = 0; rr < 4; ++rr) {
      const int c = (w + 8 * j) * 16 + (l >> 4) * 4 + rr;
      const size_t base = ((size_t)(n * 512 + c)) * 4096 + (size_t)p0;
      float sy = 0.f, sq = 0.f;
      #pragma unroll
      for (int ct = 0; ct < 4; ++ct) {
        const int ml = ct * 16 + (l & 15);
        const float y = gmm * accg[j][ct][rr] + x[base + ml];
        out[base + ml] = y;
        sy += y; sq += y * y;
      }
      sy = red16(sy);
      sq = red16(sq);
      if ((l & 15) == 0) {
        psum[(size_t)c * 512 + bid] = sy;
        psq [(size_t)c * 512 + bid] = sq;
      }
    }
  }
}

// ---------------- BN stats / apply ----------------
__global__ __launch_bounds__(256) void stats_kernel(
    const float* __restrict__ psum, const float* __restrict__ psq,
    const float* __restrict__ bnw,  const float* __restrict__ bnb,
    float* __restrict__ aff)
{
  const int c = blockIdx.x;
  const int t = threadIdx.x;
  float s = psum[(size_t)c * 512 + t] + psum[(size_t)c * 512 + t + 256];
  float q = psq [(size_t)c * 512 + t] + psq [(size_t)c * 512 + t + 256];
  #pragma unroll
  for (int sh = 1; sh < 64; sh <<= 1) {
    s += __shfl_xor(s, sh, 64);
    q += __shfl_xor(q, sh, 64);
  }
  __shared__ float ls[4], lq[4];
  const int wv = t >> 6;
  if ((t & 63) == 0) { ls[wv] = s; lq[wv] = q; }
  __syncthreads();
  if (t == 0) {
    const float S = ls[0] + ls[1] + ls[2] + ls[3];
    const float Q = lq[0] + lq[1] + lq[2] + lq[3];
    const float mean = S * (1.0f / 32768.0f);
    const float var  = Q * (1.0f / 32768.0f) - mean * mean;
    const float inv  = rsqrtf(var + 1e-5f);
    const float sc   = bnw[c] * inv;
    aff[2 * c]     = sc;
    aff[2 * c + 1] = bnb[c] - mean * sc;
  }
}

__global__ __launch_bounds__(256) void norm_kernel(float* __restrict__ out,
                                                   const float* __restrict__ aff)
{
  f32x4* p = (f32x4*)out;
  for (int i = blockIdx.x * blockDim.x + threadIdx.x; i < 4194304;
       i += gridDim.x * blockDim.x) {
    const int c = (i >> 10) & 511;
    const float sc = aff[2 * c], sh = aff[2 * c + 1];
    f32x4 v = p[i];
    #pragma unroll
    for (int k = 0; k < 4; ++k) v[k] = v[k] * sc + sh;
    p[i] = v;
  }
}

extern "C" void kernel_launch(void* const* d_in, const int* in_sizes, int n_in,
                              void* d_out, int out_size, void* d_ws, size_t ws_size,
                              hipStream_t stream) {
  const float* x     = (const float*)d_in[0];
  const float* theta = (const float*)d_in[1];
  const float* proto = (const float*)d_in[2];
  const float* fc1w  = (const float*)d_in[3];
  const float* fc1b  = (const float*)d_in[4];
  const float* fc2w  = (const float*)d_in[5];
  const float* fc2b  = (const float*)d_in[6];
  const float* ow    = (const float*)d_in[7];
  const float* gamma = (const float*)d_in[8];
  const float* bnw   = (const float*)d_in[9];
  const float* bnb   = (const float*)d_in[10];
  char*  ws   = (char*)d_ws;
  char*  ob   = (char*)d_out;
  float* out  = (float*)d_out;
  float* psum = (float*)(ws + OFF_PSUM);
  float* psq  = (float*)(ws + OFF_PSQ);
  float* aff  = (float*)(ws + OFF_AFF);

  prep_kernel<<<4096, 256, 0, stream>>>(theta, proto, fc1w, fc2w, ow, ws);

  const bool big_ws = (ws_size >= WS_NEED);

  if (big_ws) {
    __bf16* A2 = (__bf16*)(ws + OFF_A2);
    (void)hipFuncSetAttribute((const void*)k12_attn, hipFuncAttributeMaxDynamicSharedMemorySize, SMEM_B);
    (void)hipFuncSetAttribute((const void*)k3_fc1,   hipFuncAttributeMaxDynamicSharedMemorySize, SMEM_2W);
    (void)hipFuncSetAttribute((const void*)k4_fc2,   hipFuncAttributeMaxDynamicSharedMemorySize, SMEM_2W);
    (void)hipFuncSetAttribute((const void*)k5_rd,    hipFuncAttributeMaxDynamicSharedMemorySize, SMEM_2W);
    (void)hipFuncSetAttribute((const void*)k6_out,   hipFuncAttributeMaxDynamicSharedMemorySize, SMEM_1W);
    k12_attn<<<512, 512, SMEM_B,  stream>>>(x, ws, ob);
    k3_fc1  <<<512, 512, SMEM_2W, stream>>>(ws, fc1b, ob);
    k4_fc2  <<<512, 512, SMEM_2W, stream>>>(ws, fc2b, ob, A2);
    k5_rd   <<<512, 512, SMEM_2W, stream>>>(ws, A2);
    k6_out  <<<512, 512, SMEM_1W, stream>>>(x, ws, gamma, A2, out, psum, psq);
  } else {
    (void)hipFuncSetAttribute((const void*)megaF_kernel,
                              hipFuncAttributeMaxDynamicSharedMemorySize, SMEM_B);
    megaF_kernel<<<512, 512, SMEM_B, stream>>>(x, ws, fc1b, fc2b, gamma, out, psum, psq);
  }

  stats_kernel<<<512, 256, 0, stream>>>(psum, psq, bnw, bnb, aff);
  norm_kernel<<<2048, 256, 0, stream>>>(out, aff);
}

// Round 13
// 202.277 us; speedup vs baseline: 1.4224x; 1.3984x over previous
//
#include <hip/hip_runtime.h>

#define DI __device__ __forceinline__

using bf16x8 = __attribute__((ext_vector_type(8))) __bf16;
using bf16x4 = __attribute__((ext_vector_type(4))) __bf16;
using f32x4  = __attribute__((ext_vector_type(4))) float;

typedef unsigned short u16;
typedef unsigned int   u32;

static constexpr float SM_SCALE = 0.0625f;     // 1/sqrt(FEAT=256)
static constexpr float LAMBD    = 1.0f / 512.0f;

// ---------------- workspace byte offsets ----------------
static constexpr size_t OFF_THETA  = 0;         // bf16 [256][512]
static constexpr size_t OFF_PROTOT = 262144;    // bf16 [512][256]  (proto^T)
static constexpr size_t OFF_PROTO  = 524288;    // bf16 [256][512]
static constexpr size_t OFF_FC1    = 786432;    // bf16 [512][512]
static constexpr size_t OFF_FC2    = 1310720;   // bf16 [512][512]
static constexpr size_t OFF_O      = 1835008;   // bf16 [512][256]
static constexpr size_t OFF_PSUM   = 2097152;   // f32 [512 ch][512 blk]
static constexpr size_t OFF_PSQ    = 3145728;   // f32 [512 ch][512 blk]
static constexpr size_t OFF_AFF    = 4194304;   // f32 [512][2]

// ---------------- LDS: two 32 KiB A-windows + reduce scratch ----------------
static constexpr int AB0 = 0;        // [64 rows][256 k] bf16, pitch 512B, swizzled
static constexpr int AB1 = 32768;    // k/col window 256..511
static constexpr int SCR = 65536;    // 2x2048 rrb + 2x256 rfb
static constexpr int SMEM_BYTES = 70144;

DI u16 f2b(float f) {
  union { float f; u32 u; } c; c.f = f;
  u32 r = c.u + 0x7FFFu + ((c.u >> 16) & 1u);   // RNE
  return (u16)(r >> 16);
}

// ---------------- prep: weights f32 -> bf16 (+ proto transpose) ----------------
__global__ __launch_bounds__(256) void prep_kernel(
    const float* __restrict__ theta, const float* __restrict__ proto,
    const float* __restrict__ fc1,   const float* __restrict__ fc2,
    const float* __restrict__ ow,    char* __restrict__ ws)
{
  u16* w_theta  = (u16*)(ws + OFF_THETA);
  u16* w_protoT = (u16*)(ws + OFF_PROTOT);
  u16* w_proto  = (u16*)(ws + OFF_PROTO);
  u16* w_fc1    = (u16*)(ws + OFF_FC1);
  u16* w_fc2    = (u16*)(ws + OFF_FC2);
  u16* w_o      = (u16*)(ws + OFF_O);
  for (int i = blockIdx.x * blockDim.x + threadIdx.x; i < 1048576;
       i += gridDim.x * blockDim.x) {
    if (i < 131072) { w_theta[i] = f2b(theta[i]); }
    else if (i < 262144) { int j = i - 131072; int k = j >> 8, f = j & 255;
                           w_protoT[j] = f2b(proto[f * 512 + k]); }
    else if (i < 393216) { int j = i - 262144; w_proto[j] = f2b(proto[j]); }
    else if (i < 655360) { int j = i - 393216; w_fc1[j] = f2b(fc1[j]); }
    else if (i < 917504) { int j = i - 655360; w_fc2[j] = f2b(fc2[j]); }
    else                 { int j = i - 917504; w_o[j]   = f2b(ow[j]); }
  }
}

// ---------------- barrier: lgkm drain only (global loads stay in flight) ----------
DI void bar() {
  asm volatile("s_waitcnt lgkmcnt(0)" ::: "memory");
  __builtin_amdgcn_s_barrier();
}

// ---------------- LDS fragment access: [row][k] bf16, pitch 512B, swizzled ----------
DI bf16x8 ld_frag(const char* base, int row, int kbyte) {
  return *(const bf16x8*)(base + row * 512 + (kbyte ^ ((row & 7) << 4)));
}

// ---------------- K=256-window GEMM, B direct from global (L2), reg dbuf ----------
template<int W, int CT>
DI void gemm_win(f32x4 (&acc)[4][CT], const char* awin,
                 const __bf16* __restrict__ wbase, int col0, int kw0,
                 int w, int l) {
  const int g  = l >> 4;
  const int lr = l & 15;
  const __bf16* wp[CT];
  #pragma unroll
  for (int j = 0; j < CT; ++j)
    wp[j] = wbase + (size_t)(col0 + ((w + 8 * j) << 4) + lr) * W + kw0 + g * 8;
  bf16x8 bc[CT];
  #pragma unroll
  for (int j = 0; j < CT; ++j) bc[j] = *(const bf16x8*)wp[j];
  #pragma unroll
  for (int kk = 0; kk < 8; ++kk) {
    bf16x8 af[4];
    #pragma unroll
    for (int r0 = 0; r0 < 4; ++r0)
      af[r0] = ld_frag(awin, r0 * 16 + lr, kk * 64 + g * 16);
    bf16x8 bn[CT];
    if (kk < 7) {
      #pragma unroll
      for (int j = 0; j < CT; ++j) bn[j] = *(const bf16x8*)(wp[j] + (kk + 1) * 32);
    }
    #pragma unroll
    for (int j = 0; j < CT; ++j)
      #pragma unroll
      for (int r0 = 0; r0 < 4; ++r0)
        acc[r0][j] = __builtin_amdgcn_mfma_f32_16x16x32_bf16(af[r0], bc[j], acc[r0][j], 0, 0, 0);
    if (kk < 7) {
      #pragma unroll
      for (int j = 0; j < CT; ++j) bc[j] = bn[j];
    }
  }
}

// ---------------- fragment stores to a 256-wide A-window (swizzled) -------
template<int CT>
DI void store_f32(char* aw, const f32x4 (&v)[4][CT], int w, int l) {
  #pragma unroll
  for (int j = 0; j < CT; ++j) {
    const int col = (w + 8 * j) * 16 + (l & 15);
    #pragma unroll
    for (int r0 = 0; r0 < 4; ++r0)
      #pragma unroll
      for (int rr = 0; rr < 4; ++rr) {
        const int row = r0 * 16 + (l >> 4) * 4 + rr;
        *(__bf16*)(aw + row * 512 + ((col * 2) ^ ((row & 7) << 4))) = (__bf16)v[r0][j][rr];
      }
  }
}
// store two coltiles v[r0][jb+0..1] of a [4][4] bf16 fragment set
DI void store_pair(char* aw, const bf16x4 (&v)[4][4], int jb, int w, int l) {
  #pragma unroll
  for (int j = 0; j < 2; ++j) {
    const int col = (w + 8 * j) * 16 + (l & 15);
    #pragma unroll
    for (int r0 = 0; r0 < 4; ++r0)
      #pragma unroll
      for (int rr = 0; rr < 4; ++rr) {
        const int row = r0 * 16 + (l >> 4) * 4 + rr;
        *(__bf16*)(aw + row * 512 + ((col * 2) ^ ((row & 7) << 4))) = v[r0][jb + j][rr];
      }
  }
}
DI void store_pair2(char* aw, const bf16x4 (&v)[4][2], int w, int l) {
  #pragma unroll
  for (int j = 0; j < 2; ++j) {
    const int col = (w + 8 * j) * 16 + (l & 15);
    #pragma unroll
    for (int r0 = 0; r0 < 4; ++r0)
      #pragma unroll
      for (int rr = 0; rr < 4; ++rr) {
        const int row = r0 * 16 + (l >> 4) * 4 + rr;
        *(__bf16*)(aw + row * 512 + ((col * 2) ^ ((row & 7) << 4))) = v[r0][j][rr];
      }
  }
}

DI float red16(float v) {
  #pragma unroll
  for (int s = 1; s < 16; s <<= 1) v += __shfl_xor(v, s, 64);
  return v;
}

// cross-wave per-row sum through SCR
DI void row_round(char* smem, int round, float (&part)[4][4], float (&res)[4][4],
                  int w, int l, int tid) {
  float* rrb = (float*)(smem + SCR + round * 2048);
  float* rfb = (float*)(smem + SCR + 4096 + round * 256);
  const int g = l >> 4;
  if ((l & 15) == 0) {
    #pragma unroll
    for (int r0 = 0; r0 < 4; ++r0)
      #pragma unroll
      for (int rr = 0; rr < 4; ++rr)
        rrb[(r0 * 16 + g * 4 + rr) * 8 + w] = part[r0][rr];
  }
  bar();
  if (tid < 64) {
    float m = 0.0f;
    #pragma unroll
    for (int q = 0; q < 8; ++q) m += rrb[tid * 8 + q];
    rfb[tid] = m;
  }
  bar();
  #pragma unroll
  for (int r0 = 0; r0 < 4; ++r0)
    #pragma unroll
    for (int rr = 0; rr < 4; ++rr)
      res[r0][rr] = rfb[r0 * 16 + g * 4 + rr];
}

// ---------------- mega: fused chain for 64 pixel-rows per block ----------------
// waves_per_eu(4,4): min=4 keeps the 128-VGPR budget (2 blocks/CU), max=4 stops
// clang from squeezing to 64 VGPR + scratch spill (the VGPR=64/WRITE-inflation
// pathology seen in every __launch_bounds__(512,4) build this session).
__global__ __launch_bounds__(512) __attribute__((amdgpu_waves_per_eu(4, 4)))
void mega_kernel(
    const float* __restrict__ x, const char* __restrict__ ws,
    const float* __restrict__ fc1b, const float* __restrict__ fc2b,
    const float* __restrict__ gammap, float* __restrict__ out,
    float* __restrict__ psum, float* __restrict__ psq)
{
  extern __shared__ __align__(16) char smem[];
  const int tid = threadIdx.x;
  const int w   = tid >> 6;
  const int l   = tid & 63;
  const int bid = blockIdx.x;
  const int m0  = bid << 6;
  const int n   = m0 >> 12;
  const int p0  = m0 & 4095;

  const __bf16* w_theta  = (const __bf16*)(ws + OFF_THETA);
  const __bf16* w_protoT = (const __bf16*)(ws + OFF_PROTOT);
  const __bf16* w_proto  = (const __bf16*)(ws + OFF_PROTO);
  const __bf16* w_fc1    = (const __bf16*)(ws + OFF_FC1);
  const __bf16* w_fc2    = (const __bf16*)(ws + OFF_FC2);
  const __bf16* w_o      = (const __bf16*)(ws + OFF_O);

  char* ab0 = smem + AB0;
  char* ab1 = smem + AB1;

  const f32x4 zz = {0.f, 0.f, 0.f, 0.f};

  // ---- stage A: Q[64][256] = X[64][512] @ theta^T (channel windows of 256)
  f32x4 accq[4][2];
  #pragma unroll
  for (int a = 0; a < 4; ++a) { accq[a][0] = zz; accq[a][1] = zz; }
  #pragma unroll
  for (int ah = 0; ah < 2; ++ah) {
    bar();
    #pragma unroll
    for (int q = 0; q < 4; ++q) {
      const int cl = q * 64 + (tid >> 3);
      const int c  = ah * 256 + cl;
      const int j0 = (tid & 7) * 8;
      const float* xp = x + ((size_t)(n * 512 + c)) * 4096 + (size_t)(p0 + j0);
      f32x4 v0 = *(const f32x4*)xp;
      f32x4 v1 = *(const f32x4*)(xp + 4);
      #pragma unroll
      for (int i = 0; i < 8; ++i) {
        const float f = (i < 4) ? v0[i] : v1[i - 4];
        const int row = j0 + i;
        *(__bf16*)(ab0 + row * 512 + ((cl * 2) ^ ((row & 7) << 4))) = (__bf16)f;
      }
    }
    bar();
    gemm_win<512, 2>(accq, ab0, w_theta, 0, ah * 256, w, l);
  }

  // ---- Q -> AB0 (bf16)
  bar();
  store_f32<2>(ab0, accq, w, l);
  bar();

  // ---- stage B+C: logits halves -> exp (no max-sub; scaled logits small, f32-safe)
  bf16x4 pe[4][4];              // e-values -> attn A1 (bf16)
  float  se[4][4];
  #pragma unroll
  for (int r0 = 0; r0 < 4; ++r0)
    #pragma unroll
    for (int rr = 0; rr < 4; ++rr) se[r0][rr] = 0.f;
  #pragma unroll
  for (int h = 0; h < 2; ++h) {
    f32x4 accB[4][2];
    #pragma unroll
    for (int a = 0; a < 4; ++a) { accB[a][0] = zz; accB[a][1] = zz; }
    gemm_win<256, 2>(accB, ab0, w_protoT, h * 256, 0, w, l);
    #pragma unroll
    for (int r0 = 0; r0 < 4; ++r0)
      #pragma unroll
      for (int j = 0; j < 2; ++j)
        #pragma unroll
        for (int rr = 0; rr < 4; ++rr) {
          const float e = __expf(accB[r0][j][rr] * SM_SCALE);
          pe[r0][2 * h + j][rr] = (__bf16)e;
          se[r0][rr] += e;
        }
  }
  {
    float rres[4][4];
    #pragma unroll
    for (int r0 = 0; r0 < 4; ++r0)
      #pragma unroll
      for (int rr = 0; rr < 4; ++rr) se[r0][rr] = red16(se[r0][rr]);
    row_round(smem, 0, se, rres, w, l, tid);
    #pragma unroll
    for (int r0 = 0; r0 < 4; ++r0)
      #pragma unroll
      for (int rr = 0; rr < 4; ++rr) {
        const float rinv = 1.0f / rres[r0][rr];
        float s2 = 0.f;
        #pragma unroll
        for (int ft = 0; ft < 4; ++ft) {
          const float s = (float)pe[r0][ft][rr] * rinv;
          const float t = s - LAMBD;
          const float a = __fdividef(fmaxf(t, 0.f) * s, fabsf(t) + 1e-12f);
          pe[r0][ft][rr] = (__bf16)a;
          s2 += a;
        }
        se[r0][rr] = red16(s2);
      }
    row_round(smem, 1, se, rres, w, l, tid);
    #pragma unroll
    for (int r0 = 0; r0 < 4; ++r0)
      #pragma unroll
      for (int rr = 0; rr < 4; ++rr) {
        const float rinv = 1.0f / (rres[r0][rr] + 1e-12f);
        #pragma unroll
        for (int ft = 0; ft < 4; ++ft)
          pe[r0][ft][rr] = (__bf16)((float)pe[r0][ft][rr] * rinv);
      }
  }
  // pe now holds A1 (attn) in bf16 regs

  // ---- A1 -> AB0 (cols 0..255) + AB1 (cols 256..511)
  bar();
  store_pair(ab0, pe, 0, w, l);
  store_pair(ab1, pe, 2, w, l);
  bar();

  // ---- stage D: R = relu(A1 @ fc1^T + b1), zero interior barriers
  bf16x4 prb[2][4][2];
  #pragma unroll
  for (int rh = 0; rh < 2; ++rh) {
    f32x4 accd[4][2];
    #pragma unroll
    for (int a = 0; a < 4; ++a) { accd[a][0] = zz; accd[a][1] = zz; }
    gemm_win<512, 2>(accd, ab0, w_fc1, rh * 256, 0,   w, l);
    gemm_win<512, 2>(accd, ab1, w_fc1, rh * 256, 256, w, l);
    #pragma unroll
    for (int j = 0; j < 2; ++j) {
      const float b1 = fc1b[rh * 256 + (w + 8 * j) * 16 + (l & 15)];
      #pragma unroll
      for (int r0 = 0; r0 < 4; ++r0)
        #pragma unroll
        for (int rr = 0; rr < 4; ++rr)
          prb[rh][r0][j][rr] = (__bf16)fmaxf(accd[r0][j][rr] + b1, 0.f);
    }
  }

  // ---- R -> AB0/AB1
  bar();
  store_pair2(ab0, prb[0], w, l);
  store_pair2(ab1, prb[1], w, l);
  bar();

  // ---- stage E: A2 = A1 + R @ fc2^T + b2 (acc init from pe + b2)
  bf16x4 pab[4][4];
  #pragma unroll
  for (int ch = 0; ch < 2; ++ch) {
    f32x4 acce[4][2];
    #pragma unroll
    for (int jj = 0; jj < 2; ++jj) {
      const float b2 = fc2b[ch * 256 + (w + 8 * jj) * 16 + (l & 15)];
      #pragma unroll
      for (int r0 = 0; r0 < 4; ++r0)
        #pragma unroll
        for (int rr = 0; rr < 4; ++rr)
          acce[r0][jj][rr] = (float)pe[r0][2 * ch + jj][rr] + b2;
    }
    gemm_win<512, 2>(acce, ab0, w_fc2, ch * 256, 0,   w, l);
    gemm_win<512, 2>(acce, ab1, w_fc2, ch * 256, 256, w, l);
    #pragma unroll
    for (int r0 = 0; r0 < 4; ++r0)
      #pragma unroll
      for (int jj = 0; jj < 2; ++jj)
        #pragma unroll
        for (int rr = 0; rr < 4; ++rr) pab[r0][2 * ch + jj][rr] = (__bf16)acce[r0][jj][rr];
  }

  // ---- A2 -> AB0/AB1
  bar();
  store_pair(ab0, pab, 0, w, l);
  store_pair(ab1, pab, 2, w, l);
  bar();

  // ---- stage F: Rd[64][256] = A2 @ proto^T
  f32x4 accf[4][2];
  #pragma unroll
  for (int a = 0; a < 4; ++a) { accf[a][0] = zz; accf[a][1] = zz; }
  gemm_win<512, 2>(accf, ab0, w_proto, 0, 0,   w, l);
  gemm_win<512, 2>(accf, ab1, w_proto, 0, 256, w, l);

  // ---- Rd -> AB0
  bar();
  store_f32<2>(ab0, accf, w, l);
  bar();

  // ---- stage G (swapped operands): yT[512 c][64 m] = o_w @ Rd^T
  f32x4 accg[4][4];
  #pragma unroll
  for (int a = 0; a < 4; ++a)
    #pragma unroll
    for (int b = 0; b < 4; ++b) accg[a][b] = zz;
  {
    const int g  = l >> 4;
    const int lr = l & 15;
    const __bf16* wp[4];
    #pragma unroll
    for (int j = 0; j < 4; ++j)
      wp[j] = w_o + (size_t)(((w + 8 * j) << 4) + lr) * 256 + g * 8;
    #pragma unroll
    for (int kk = 0; kk < 8; ++kk) {
      bf16x8 of[4];
      #pragma unroll
      for (int j = 0; j < 4; ++j) of[j] = *(const bf16x8*)(wp[j] + kk * 32);
      #pragma unroll
      for (int ct = 0; ct < 4; ++ct) {
        bf16x8 rdv = ld_frag(ab0, ct * 16 + lr, kk * 64 + g * 16);
        #pragma unroll
        for (int j = 0; j < 4; ++j)
          accg[j][ct] = __builtin_amdgcn_mfma_f32_16x16x32_bf16(of[j], rdv, accg[j][ct], 0, 0, 0);
      }
    }
  }

  // ---- epilogue: y = gamma*conv + x (coalesced along p), BN partials per channel
  const float gmm = gammap[0];
  #pragma unroll
  for (int j = 0; j < 4; ++j) {
    #pragma unroll
    for (int rr = 0; rr < 4; ++rr) {
      const int c = (w + 8 * j) * 16 + (l >> 4) * 4 + rr;
      const size_t base = ((size_t)(n * 512 + c)) * 4096 + (size_t)p0;
      float sy = 0.f, sq = 0.f;
      #pragma unroll
      for (int ct = 0; ct < 4; ++ct) {
        const int ml = ct * 16 + (l & 15);
        const float y = gmm * accg[j][ct][rr] + x[base + ml];
        out[base + ml] = y;
        sy += y; sq += y * y;
      }
      sy = red16(sy);
      sq = red16(sq);
      if ((l & 15) == 0) {
        psum[(size_t)c * 512 + bid] = sy;
        psq [(size_t)c * 512 + bid] = sq;
      }
    }
  }
}

// ---------------- BN stats ----------------
__global__ __launch_bounds__(256) void stats_kernel(
    const float* __restrict__ psum, const float* __restrict__ psq,
    const float* __restrict__ bnw,  const float* __restrict__ bnb,
    float* __restrict__ aff)
{
  const int c = blockIdx.x;
  const int t = threadIdx.x;
  float s = psum[(size_t)c * 512 + t] + psum[(size_t)c * 512 + t + 256];
  float q = psq [(size_t)c * 512 + t] + psq [(size_t)c * 512 + t + 256];
  #pragma unroll
  for (int sh = 1; sh < 64; sh <<= 1) {
    s += __shfl_xor(s, sh, 64);
    q += __shfl_xor(q, sh, 64);
  }
  __shared__ float ls[4], lq[4];
  const int wv = t >> 6;
  if ((t & 63) == 0) { ls[wv] = s; lq[wv] = q; }
  __syncthreads();
  if (t == 0) {
    const float S = ls[0] + ls[1] + ls[2] + ls[3];
    const float Q = lq[0] + lq[1] + lq[2] + lq[3];
    const float mean = S * (1.0f / 32768.0f);
    const float var  = Q * (1.0f / 32768.0f) - mean * mean;
    const float inv  = rsqrtf(var + 1e-5f);
    const float sc   = bnw[c] * inv;
    aff[2 * c]     = sc;
    aff[2 * c + 1] = bnb[c] - mean * sc;
  }
}

// ---------------- BN apply (full tensor: 4,194,304 f32x4) ----------------
__global__ __launch_bounds__(256) void norm_kernel(float* __restrict__ out,
                                                   const float* __restrict__ aff)
{
  f32x4* p = (f32x4*)out;
  for (int i = blockIdx.x * blockDim.x + threadIdx.x; i < 4194304;
       i += gridDim.x * blockDim.x) {
    const int c = (i >> 10) & 511;
    const float sc = aff[2 * c], sh = aff[2 * c + 1];
    f32x4 v = p[i];
    #pragma unroll
    for (int k = 0; k < 4; ++k) v[k] = v[k] * sc + sh;
    p[i] = v;
  }
}

extern "C" void kernel_launch(void* const* d_in, const int* in_sizes, int n_in,
                              void* d_out, int out_size, void* d_ws, size_t ws_size,
                              hipStream_t stream) {
  const float* x     = (const float*)d_in[0];
  const float* theta = (const float*)d_in[1];
  const float* proto = (const float*)d_in[2];
  const float* fc1w  = (const float*)d_in[3];
  const float* fc1b  = (const float*)d_in[4];
  const float* fc2w  = (const float*)d_in[5];
  const float* fc2b  = (const float*)d_in[6];
  const float* ow    = (const float*)d_in[7];
  const float* gamma = (const float*)d_in[8];
  const float* bnw   = (const float*)d_in[9];
  const float* bnb   = (const float*)d_in[10];
  char*  ws   = (char*)d_ws;
  float* out  = (float*)d_out;
  float* psum = (float*)(ws + OFF_PSUM);
  float* psq  = (float*)(ws + OFF_PSQ);
  float* aff  = (float*)(ws + OFF_AFF);

  prep_kernel<<<4096, 256, 0, stream>>>(theta, proto, fc1w, fc2w, ow, ws);

  (void)hipFuncSetAttribute((const void*)mega_kernel,
                            hipFuncAttributeMaxDynamicSharedMemorySize, SMEM_BYTES);
  mega_kernel<<<512, 512, SMEM_BYTES, stream>>>(x, ws, fc1b, fc2b, gamma, out, psum, psq);

  stats_kernel<<<512, 256, 0, stream>>>(psum, psq, bnw, bnb, aff);
  norm_kernel<<<2048, 256, 0, stream>>>(out, aff);
}